// Round 7
// baseline (518.028 us; speedup 1.0000x reference)
//
#include <hip/hip_runtime.h>
#include <stdint.h>

#define DEV __device__ __forceinline__

typedef _Float16 half2_t __attribute__((ext_vector_type(2)));
typedef _Float16 half4_t __attribute__((ext_vector_type(4)));
typedef __bf16   bf16x8  __attribute__((ext_vector_type(8)));
typedef float    floatx4 __attribute__((ext_vector_type(4)));
typedef float    floatx2 __attribute__((ext_vector_type(2)));

DEV float fdot2f(half2_t a, half2_t b, float c) {
#if __has_builtin(__builtin_amdgcn_fdot2)
  return __builtin_amdgcn_fdot2(a, b, c, false);
#else
  return c + (float)a[0] * (float)b[0] + (float)a[1] * (float)b[1];
#endif
}

DEV half2_t pkh2(float a, float b) {
#if __has_builtin(__builtin_amdgcn_cvt_pkrtz)
  return __builtin_bit_cast(half2_t, __builtin_amdgcn_cvt_pkrtz(a, b));
#else
  half2_t r; r[0] = (_Float16)a; r[1] = (_Float16)b; return r;
#endif
}

DEV uint32_t f2bf(float f) {  // fp32 -> bf16 bits, RNE
  uint32_t u = __float_as_uint(f);
  return (u + 0x7FFFu + ((u >> 16) & 1u)) >> 16;
}

// Raw workgroup barrier: drains LDS ops only (lgkmcnt), NOT vmcnt.
// Global prefetch loads stay in flight across the barrier (T3/T4);
// their completion is enforced by normal register dependencies.
DEV void tile_barrier() {
  __builtin_amdgcn_sched_barrier(0);
  asm volatile("s_waitcnt lgkmcnt(0)" ::: "memory");
  __builtin_amdgcn_s_barrier();
  __builtin_amdgcn_sched_barrier(0);
}

// ---------------------------------------------------------------------------
// Correlation (all levels, one launch).
// Big levels (0,1): 32x16 px tile, 256 thr, 2 px/thread, conflict-free LDS
// (even stride 40, b64 window reads). Staging TRIPLE-buffered in regs
// (flA/flB/flC, hand-rotated, unroll-by-3): data for chunk k+1's LDS store is
// loaded 2 chunks earlier -> ~2 chunks (~1400+ cyc) of HBM-latency cover.
// Raw s_barrier (lgkmcnt-only) keeps those loads in flight across chunks.
// Level 2: 16x16 1px/thread, same 3-rotation. Small levels: 1 thr/output.
// ---------------------------------------------------------------------------
struct CorrCfg {
  const float* gx[6]; const float* gxp[6];
  int wg_start[2];     // big levels 0,1
  int mid_start;       // level 2
  int small_start[3];  // levels 3-5
  int S[2], C[2], tiles_x[2], tiles_pb[2], cpl[2];
  int mcpl;
  int sS[3], sC[3], sNspl[3];
  long long poff[2], mpoff, spoff[3];
};

__global__ __launch_bounds__(256)
void corr_kernel(CorrCfg cfg, _Float16* __restrict__ partial)
{
  __shared__ half2_t ldsbuf[2][2][22*40] __attribute__((aligned(16)));
  const int tid = threadIdx.x;
  int wg = blockIdx.x;

  if (wg >= cfg.small_start[0]) {
    // ---- small path (levels 3-5) ----
    int lvl = (wg >= cfg.small_start[2]) ? 2 : (wg >= cfg.small_start[1]) ? 1 : 0;
    long long i = (long long)(wg - cfg.small_start[lvl])*256 + tid;
    const int S = cfg.sS[lvl], C = cfg.sC[lvl], SS = S*S;
    const int nsp = cfg.sNspl[lvl];
    const long long per = (long long)8*49*SS;
    if (i >= (long long)nsp*per) return;
    int sp = (int)(i / per);
    long long rem = i - (long long)sp*per;
    const int cpl = C / nsp, cbase = sp * cpl;
    const float* X  = cfg.gx[lvl+3];
    const float* XP = cfg.gxp[lvl+3];
    int xc_ = (int)(rem % S); int yc = (int)((rem/S) % S);
    int d = (int)((rem/SS) % 49); int b = (int)(rem/((long long)49*SS));
    int yy = yc + d/7 - 3, xx = xc_ + (d%7) - 3;
    float s = 0.f;
    if (yy >= 0 && yy < S && xx >= 0 && xx < S) {
      const float* xb = X  + ((size_t)b*C + cbase)*SS + (size_t)yc*S + xc_;
      const float* pb = XP + ((size_t)b*C + cbase)*SS + (size_t)yy*S + xx;
      #pragma unroll 8
      for (int c = 0; c < cpl; ++c) s += xb[(size_t)c*SS] * pb[(size_t)c*SS];
    }
    partial[cfg.spoff[lvl] + (long long)sp*per + rem] = (_Float16)s;
    return;
  }

  if (wg >= cfg.mid_start) {
    // ---- mid path (level 2, S=16, C=512): 1 px/thread, b32 windows ----
    constexpr int NT = 256, MS = 16, MC = 512;
    constexpr int ROWS = 22, COLS = 22, ST = 23;
    constexpr int SLOTS = ROWS * 6 * 2;       // 264
    constexpr int PER = 2;
    int rel = wg - cfg.mid_start;
    const int cpl = cfg.mcpl;
    const int sp = rel >> 3;
    const int b = rel & 7;
    const int tx = tid & 15, ty = tid >> 4;
    const int cbase = sp * cpl;
    const size_t SS = (size_t)MS*MS;
    const float* Xb  = cfg.gx[2]  + (size_t)b*MC*SS;
    const float* XPb = cfg.gxp[2] + (size_t)b*MC*SS;
    const size_t qoff = (size_t)ty*MS + tx;

    int f_go[PER], f_base[PER], f_col0[PER], f_pr[PER];
    bool f_ok[PER], f_val[PER];
    #pragma unroll
    for (int s = 0; s < PER; ++s) {
      int i = tid + s*NT;
      bool val = (i < SLOTS);
      int ii = val ? i : 0;
      int pr = ii & 1;
      int rest = ii >> 1;
      int q = rest % 6;
      int r = rest / 6;
      int gy = r - 3;
      int gx0 = -4 + 4*q;
      bool ok = val && gy >= 0 && gy < MS && gx0 >= 0 && (gx0 + 3) < MS;
      f_val[s] = val; f_ok[s] = ok; f_pr[s] = pr;
      f_go[s] = ok ? gy*MS + gx0 : 0;
      f_col0[s] = 4*q - 1;
      f_base[s] = r*ST;
    }

    float acc[49];
    #pragma unroll
    for (int d = 0; d < 49; ++d) acc[d] = 0.f;
    floatx4 flA[PER][2], flB[PER][2], flC[PER][2];
    float xc[4], xn[4];

#define MFILL_LOAD(fl, c0v) { \
  _Pragma("unroll") for (int s = 0; s < PER; ++s) { \
    const float* p_ = XPb + (size_t)(cbase + (c0v) + 2*f_pr[s])*SS + f_go[s]; \
    if (f_ok[s]) { fl[s][0] = *(const floatx4*)p_; fl[s][1] = *(const floatx4*)(p_ + SS); } \
    else { fl[s][0] = (floatx4)0.f; fl[s][1] = (floatx4)0.f; } } }

#define MXLOAD(dst, c0v) { \
  _Pragma("unroll") for (int c = 0; c < 4; ++c) \
    dst[c] = Xb[(size_t)(cbase + (c0v) + c)*SS + qoff]; }

#define MFILL_STORE(bbv, fl) { \
  _Pragma("unroll") for (int s = 0; s < PER; ++s) if (f_val[s]) { \
    half2_t* plane_ = &ldsbuf[bbv][f_pr[s]][0]; \
    _Pragma("unroll") for (int j = 0; j < 4; ++j) { \
      int col_ = f_col0[s] + j; \
      if (col_ >= 0 && col_ < COLS) \
        plane_[f_base[s] + col_] = pkh2(fl[s][0][j], fl[s][1][j]); } } }

#define MCOMPUTE(bbv) { \
  _Pragma("unroll") for (int pr = 0; pr < 2; ++pr) { \
    half2_t xq = pkh2(xc[2*pr], xc[2*pr+1]); \
    _Pragma("unroll") for (int di = 0; di < 7; ++di) { \
      const half2_t* row_ = &ldsbuf[bbv][pr][(ty+di)*ST + tx]; \
      _Pragma("unroll") for (int dj = 0; dj < 7; ++dj) \
        acc[di*7+dj] = fdot2f(xq, row_[dj], acc[di*7+dj]); } } }

#define MXROT { _Pragma("unroll") for (int c = 0; c < 4; ++c) xc[c] = xn[c]; }

    const int nchunk = cpl >> 2;
    MFILL_LOAD(flA, 0); MXLOAD(xc, 0);
    MFILL_LOAD(flB, 4); MXLOAD(xn, 4);
    MFILL_STORE(0, flA);
    MFILL_LOAD(flC, 8);
    tile_barrier();
    for (int k = 0; k < nchunk; k += 3) {
      { const int bb = k & 1;
        if (k+1 < nchunk) MFILL_STORE(bb^1, flB);
        if (k+3 < nchunk) MFILL_LOAD(flA, (k+3)*4);
        MCOMPUTE(bb);
        MXROT;
        if (k+2 < nchunk) MXLOAD(xn, (k+2)*4);
        tile_barrier(); }
      if (k+1 < nchunk) { const int bb = (k+1) & 1;
        if (k+2 < nchunk) MFILL_STORE(bb^1, flC);
        if (k+4 < nchunk) MFILL_LOAD(flB, (k+4)*4);
        MCOMPUTE(bb);
        MXROT;
        if (k+3 < nchunk) MXLOAD(xn, (k+3)*4);
        tile_barrier(); }
      if (k+2 < nchunk) { const int bb = (k+2) & 1;
        if (k+3 < nchunk) MFILL_STORE(bb^1, flA);
        if (k+5 < nchunk) MFILL_LOAD(flC, (k+5)*4);
        MCOMPUTE(bb);
        MXROT;
        if (k+4 < nchunk) MXLOAD(xn, (k+4)*4);
        tile_barrier(); }
    }
#undef MFILL_LOAD
#undef MXLOAD
#undef MFILL_STORE
#undef MCOMPUTE
#undef MXROT

    _Float16* P = partial + cfg.mpoff + ((size_t)sp*8 + b)*49*SS + qoff;
    #pragma unroll
    for (int d = 0; d < 49; ++d) P[(size_t)d*SS] = (_Float16)acc[d];
    return;
  }

  // ---- big path (levels 0,1): 32x16 tile, 2 px/thread, b64 windows ----
  {
    constexpr int NT = 256, TH = 16, TW = 32;
    constexpr int ROWS = TH + 6;            // 22
    constexpr int COLS = TW + 6;            // 38
    constexpr int QUADS = 10;
    constexpr int ST = TW + 8;              // 40 (even; bank-pair 20r+tx uniform)
    constexpr int SLOTS = ROWS * QUADS * 2; // 440
    constexpr int PER = 2;

    int lvl = (wg >= cfg.wg_start[1]) ? 1 : 0;
    wg -= cfg.wg_start[lvl];
    const float* X  = cfg.gx[lvl];
    const float* XP = cfg.gxp[lvl];
    const int S = cfg.S[lvl], C = cfg.C[lvl];
    const int txc = cfg.tiles_x[lvl], tpb = cfg.tiles_pb[lvl], cpl = cfg.cpl[lvl];
    const int per_split = 8 * tpb;
    const int sp = wg / per_split;
    const int rem = wg - sp*per_split;
    const int b = rem / tpb;
    const int t = rem - b*tpb;
    const int y0 = (t / txc) * TH, x0t = (t % txc) * TW;
    const int tx = tid & 15, ty = tid >> 4;
    const int cbase = sp * cpl;
    const size_t SS = (size_t)S*S;
    const float* Xb  = X  + (size_t)b*C*SS;
    const float* XPb = XP + (size_t)b*C*SS;
    const int py = y0 + ty, px = x0t + 2*tx;
    const size_t qoff = (size_t)py*S + px;

    int f_go[PER], f_base[PER], f_col0[PER], f_pr[PER];
    bool f_ok[PER], f_val[PER];
    #pragma unroll
    for (int s = 0; s < PER; ++s) {
      int i = tid + s*NT;
      bool val = (i < SLOTS);
      int ii = val ? i : 0;
      int pr = ii & 1;
      int rest = ii >> 1;
      int q = rest % QUADS;
      int r = rest / QUADS;
      int gy = y0 + r - 3;
      int gx0 = x0t - 4 + 4*q;
      bool ok = val && gy >= 0 && gy < S && gx0 >= 0 && (gx0 + 3) < S;
      f_val[s] = val; f_ok[s] = ok; f_pr[s] = pr;
      f_go[s] = ok ? gy*S + gx0 : 0;
      f_col0[s] = 4*q - 1;
      f_base[s] = r*ST;
    }

    floatx2 acc[49];
    #pragma unroll
    for (int d = 0; d < 49; ++d) acc[d] = (floatx2)0.f;
    floatx4 flA[PER][2], flB[PER][2], flC[PER][2];
    floatx2 xc[4], xn[4];

#define FILL_LOAD(fl, c0v) { \
  _Pragma("unroll") for (int s = 0; s < PER; ++s) { \
    const float* p_ = XPb + (size_t)(cbase + (c0v) + 2*f_pr[s])*SS + f_go[s]; \
    if (f_ok[s]) { fl[s][0] = *(const floatx4*)p_; fl[s][1] = *(const floatx4*)(p_ + SS); } \
    else { fl[s][0] = (floatx4)0.f; fl[s][1] = (floatx4)0.f; } } }

#define XLOAD(dst, c0v) { \
  _Pragma("unroll") for (int c = 0; c < 4; ++c) \
    dst[c] = *(const floatx2*)(Xb + (size_t)(cbase + (c0v) + c)*SS + qoff); }

#define FILL_STORE(bbv, fl) { \
  _Pragma("unroll") for (int s = 0; s < PER; ++s) if (f_val[s]) { \
    half2_t* plane_ = &ldsbuf[bbv][f_pr[s]][0]; \
    _Pragma("unroll") for (int j = 0; j < 4; ++j) { \
      int col_ = f_col0[s] + j; \
      if (col_ >= 0 && col_ < COLS) \
        plane_[f_base[s] + col_] = pkh2(fl[s][0][j], fl[s][1][j]); } } }

#define COMPUTE(bbv) { \
  _Pragma("unroll") for (int pr = 0; pr < 2; ++pr) { \
    half2_t xqa = pkh2(xc[2*pr].x, xc[2*pr+1].x); \
    half2_t xqb = pkh2(xc[2*pr].y, xc[2*pr+1].y); \
    _Pragma("unroll") for (int di = 0; di < 7; ++di) { \
      const half2_t* row_ = &ldsbuf[bbv][pr][(ty+di)*ST + 2*tx]; \
      half2_t L_[8]; \
      _Pragma("unroll") for (int k = 0; k < 4; ++k) { \
        half4_t v_ = *(const half4_t*)(row_ + 2*k); \
        L_[2*k]   = __builtin_shufflevector(v_, v_, 0, 1); \
        L_[2*k+1] = __builtin_shufflevector(v_, v_, 2, 3); } \
      _Pragma("unroll") for (int dj = 0; dj < 7; ++dj) { \
        acc[di*7+dj].x = fdot2f(xqa, L_[dj],   acc[di*7+dj].x); \
        acc[di*7+dj].y = fdot2f(xqb, L_[dj+1], acc[di*7+dj].y); } } } }

#define XROT { _Pragma("unroll") for (int c = 0; c < 4; ++c) xc[c] = xn[c]; }

    const int nchunk = cpl >> 2;
    FILL_LOAD(flA, 0); XLOAD(xc, 0);
    FILL_LOAD(flB, 4); XLOAD(xn, 4);
    FILL_STORE(0, flA);
    FILL_LOAD(flC, 8);
    tile_barrier();
    for (int k = 0; k < nchunk; k += 3) {
      { const int bb = k & 1;
        if (k+1 < nchunk) FILL_STORE(bb^1, flB);
        if (k+3 < nchunk) FILL_LOAD(flA, (k+3)*4);
        COMPUTE(bb);
        XROT;
        if (k+2 < nchunk) XLOAD(xn, (k+2)*4);
        tile_barrier(); }
      if (k+1 < nchunk) { const int bb = (k+1) & 1;
        if (k+2 < nchunk) FILL_STORE(bb^1, flC);
        if (k+4 < nchunk) FILL_LOAD(flB, (k+4)*4);
        COMPUTE(bb);
        XROT;
        if (k+3 < nchunk) XLOAD(xn, (k+3)*4);
        tile_barrier(); }
      if (k+2 < nchunk) { const int bb = (k+2) & 1;
        if (k+3 < nchunk) FILL_STORE(bb^1, flA);
        if (k+5 < nchunk) FILL_LOAD(flC, (k+5)*4);
        COMPUTE(bb);
        XROT;
        if (k+4 < nchunk) XLOAD(xn, (k+4)*4);
        tile_barrier(); }
    }
#undef FILL_LOAD
#undef XLOAD
#undef FILL_STORE
#undef COMPUTE
#undef XROT

    _Float16* P = partial + cfg.poff[lvl] + ((size_t)sp*8 + b)*49*SS + qoff;
    #pragma unroll
    for (int d = 0; d < 49; ++d) {
      half2_t pko = pkh2(acc[d].x, acc[d].y);
      *(uint32_t*)(P + (size_t)d*SS) = *(const uint32_t*)&pko;
    }
  }
}

// ---------------------------------------------------------------------------
// Weight pack: w[196][98][3][3] fp32 -> bf16 MFMA B-fragments
// layout [lvl][t:14][s:36][lane:64][j:8], k = tap*128 + ch, N padded to 224.
// ---------------------------------------------------------------------------
__global__ __launch_bounds__(256)
void pack_w_kernel(const float* __restrict__ w0, const float* __restrict__ w1,
                   const float* __restrict__ w2, const float* __restrict__ w3,
                   const float* __restrict__ w4, const float* __restrict__ w5,
                   uint16_t* __restrict__ wpack)
{
  int idx = blockIdx.x*256 + threadIdx.x;
  int lvl = idx / 258048;
  int e = idx - lvl*258048;
  const float* W = lvl==0?w0:lvl==1?w1:lvl==2?w2:lvl==3?w3:lvl==4?w4:w5;
  int j = e & 7, lane = (e >> 3) & 63, rest = e >> 9;
  int s = rest % 36, tt = rest / 36;
  int n  = tt*16 + (lane & 15);
  int ch = (s & 3)*32 + (lane >> 4)*8 + j;
  int tap = s >> 2, ky = tap/3, kx = tap - 3*ky;
  float v = 0.f;
  if (n < 196 && ch < 98) v = W[((n*98 + ch)*3 + ky)*3 + kx];
  wpack[idx] = (uint16_t)f2bf(v);
}

// ---------------------------------------------------------------------------
// Pass2: block = (lvl, b, pixel-group). Stage A: coalesced gather of split
// partials (f16) -> fp32 sum -> leaky -> corr out (coalesced) + LDS[px][99];
// h gathered likewise. Stage B: wave-per-pixel packed bf16x2 u32 stores into
// channels-last lstm_in [b][y+1][x+1][128] (fully coalesced 256B/instr).
// ---------------------------------------------------------------------------
struct P2Cfg {
  int blk_start[7];
  int S[6], nsplit[6], pxg[6], lg[6], gpb[6];
  long long poff[6], lstm_off[6], corr_off[6];
  const float* h[6];
};
__global__ __launch_bounds__(256)
void pass2_kernel(P2Cfg cfg, const _Float16* __restrict__ partial,
                  uint32_t* __restrict__ lstm, float* __restrict__ dout)
{
  __shared__ float lds[64*99];
  int blk = blockIdx.x;
  int lvl = 0;
  while (lvl < 5 && blk >= cfg.blk_start[lvl+1]) ++lvl;
  int rel = blk - cfg.blk_start[lvl];
  const int S = cfg.S[lvl], Sp = S + 2, SS = S*S;
  const int PXG = cfg.pxg[lvl], lg = cfg.lg[lvl], gpb = cfg.gpb[lvl];
  const int b = rel / gpb, g = rel - b*gpb;
  const int pixbase = g * PXG;
  const int tid = threadIdx.x;
  const int nsp = cfg.nsplit[lvl];
  const size_t spstride = (size_t)8*49*SS;
  // stage A
  for (int e = tid; e < PXG*98; e += 256) {
    int pxl = e & (PXG-1);
    int ch  = e >> lg;
    int pix = pixbase + pxl;
    float v;
    if (ch < 49) {
      const _Float16* P = partial + cfg.poff[lvl] + ((size_t)b*49 + ch)*SS + pix;
      float s = 0.f;
      for (int sp = 0; sp < nsp; ++sp) s += (float)P[(size_t)sp*spstride];
      s = s < 0.f ? 0.01f*s : s;
      dout[cfg.corr_off[lvl] + ((size_t)b*49 + ch)*SS + pix] = s;
      v = s;
    } else {
      v = cfg.h[lvl][((size_t)b*49 + (ch - 49))*SS + pix];
    }
    lds[pxl*99 + ch] = v;
  }
  __syncthreads();
  // stage B
  uint32_t* Lb = lstm + (cfg.lstm_off[lvl] >> 1);
  for (int f = tid; f < (PXG << 6); f += 256) {
    int pxl = f >> 6, c2 = f & 63;
    int pix = pixbase + pxl;
    int y = pix / S, x = pix - y*S;
    int c0 = 2*c2, c1 = c0 + 1;
    float v0 = c0 < 98 ? lds[pxl*99 + c0] : 0.f;
    float v1 = c1 < 98 ? lds[pxl*99 + c1] : 0.f;
    Lb[((size_t)(b*Sp + y + 1)*Sp + (x + 1))*64 + c2] = f2bf(v0) | (f2bf(v1) << 16);
  }
}

// ---------------------------------------------------------------------------
// FUSED Conv 3x3 (98->196) + LSTM gates. Implicit GEMM, bf16 MFMA 16x16x32,
// K = 1152, N padded to 224; A direct from channels-last lstm_in, B packed.
// A conv block holds ALL 196 channels for its 64 pixels, so the gate math
// fuses here: acc -> LDS gl[n][69] (stride 69: store lanes spread ~all banks,
// gate reads p-consecutive = conflict-free) -> i,f,o,g -> h,c to dout.
// Eliminates the 137 MB convout write + 137 MB gate re-read + one launch.
// ---------------------------------------------------------------------------
struct CCfg {
  int wg_start[7];
  int S[6], tiles_x[6], tiles_pb[6], lwsh[6], mfc[6], mgrp[6];
  long long lstm_off[6], wp_off[6], h_off[6], c_off[6];
  const float* cpre[6]; const float* bias[6];
};
__global__ __launch_bounds__(256)
void conv_kernel(CCfg cfg, const uint16_t* __restrict__ lstm,
                 const uint16_t* __restrict__ wpack, float* __restrict__ dout)
{
  __shared__ float gl[224*69];   // [n][p] staging, 61.8 KB
  int wg = blockIdx.x;
  int lvl = 0;
  while (lvl < 5 && wg >= cfg.wg_start[lvl+1]) ++lvl;
  wg -= cfg.wg_start[lvl];
  const int S = cfg.S[lvl], Sp = S + 2;
  const int lwsh = cfg.lwsh[lvl], msk = (1 << lwsh) - 1;
  const int tpb = cfg.tiles_pb[lvl];
  const int b = wg / tpb, t = wg - b*tpb;
  const int ty0 = (t / cfg.tiles_x[lvl]) << (6 - lwsh);
  const int tx0 = (t % cfg.tiles_x[lvl]) << lwsh;
  const int tid = threadIdx.x;
  const int wave = tid >> 6, lane = tid & 63;
  const int nhalf = wave & 1, mhalf = wave >> 1;
  const int mfc = cfg.mfc[lvl];
  const bool active = (mhalf < cfg.mgrp[lvl]);
  const int mi = lane & 15, q = lane >> 4;
  const int SS = S*S;

  if (active) {
    const uint16_t* lb = lstm + cfg.lstm_off[lvl] + (size_t)b*Sp*Sp*128;
    int aoff[2];
    #pragma unroll
    for (int mf = 0; mf < 2; ++mf) {
      int p = mhalf*32 + mf*16 + mi;
      int pc = p < SS ? p : 0;                 // clamp (small-level pad)
      int y = ty0 + (pc >> lwsh), xx = tx0 + (pc & msk);
      aoff[mf] = (y*Sp + xx)*128 + q*8;
    }
    const uint16_t* wb = wpack + cfg.wp_off[lvl]
                       + (size_t)(nhalf*7)*36*512 + (size_t)lane*8;
    floatx4 acc[2][7];
    #pragma unroll
    for (int mf = 0; mf < 2; ++mf)
      #pragma unroll
      for (int nt = 0; nt < 7; ++nt) acc[mf][nt] = (floatx4)0.0f;

#define CONV_LOAD(sv, AV, BV) { \
  int tap_ = (sv) >> 2, cs_ = (sv) & 3; \
  int ky_ = tap_ / 3, kx_ = tap_ - 3*ky_; \
  int ao_ = ((ky_*Sp + kx_) << 7) + (cs_ << 5); \
  _Pragma("unroll") for (int mf = 0; mf < 2; ++mf) \
    if (mf < mfc) AV[mf] = *(const bf16x8*)(lb + aoff[mf] + ao_); \
  _Pragma("unroll") for (int nt = 0; nt < 7; ++nt) \
    BV[nt] = *(const bf16x8*)(wb + (size_t)((nt)*36 + (sv))*512); }

#define CONV_MFMA(AV, BV) { \
  _Pragma("unroll") for (int nt = 0; nt < 7; ++nt) \
    _Pragma("unroll") for (int mf = 0; mf < 2; ++mf) \
      if (mf < mfc) acc[mf][nt] = __builtin_amdgcn_mfma_f32_16x16x32_bf16( \
                        AV[mf], BV[nt], acc[mf][nt], 0, 0, 0); }

    bf16x8 av0[2], bv0[7], av1[2], bv1[7];
    CONV_LOAD(0, av0, bv0);
    for (int s = 0; s < 36; s += 2) {
      CONV_LOAD(s+1, av1, bv1);
      CONV_MFMA(av0, bv0);
      if (s+2 < 36) CONV_LOAD(s+2, av0, bv0);
      CONV_MFMA(av1, bv1);
    }
#undef CONV_LOAD
#undef CONV_MFMA

    // stage acc -> LDS [n][69]
    #pragma unroll
    for (int mf = 0; mf < 2; ++mf) {
      if (mf < mfc) {
        #pragma unroll
        for (int nt = 0; nt < 7; ++nt) {
          const int n = nhalf*112 + nt*16 + mi;
          if (n < 196) {
            #pragma unroll
            for (int r = 0; r < 4; ++r) {
              const int p = mhalf*32 + mf*16 + q*4 + r;
              gl[n*69 + p] = acc[mf][nt][r];
            }
          }
        }
      }
    }
  }
  __syncthreads();

  // gate phase: wave w handles unit-group w, lanes = pixels 0..63
  const int p2 = lane;           // pixel within tile
  const int grp = wave;          // 0..3 -> units 13,13,13,10
  if (p2 < SS) {
    const int y = ty0 + (p2 >> lwsh), xx = tx0 + (p2 & msk);
    const int pix = y*S + xx;
    const float* bb2 = cfg.bias[lvl];
    const float* cp  = cfg.cpre[lvl];
    const int ch0 = grp*13, chend = (grp == 3) ? 49 : grp*13 + 13;
    for (int ch = ch0; ch < chend; ++ch) {
      float ci  = gl[ch*69 + p2]        + bb2[ch];
      float cf  = gl[(ch+49)*69 + p2]   + bb2[ch+49];
      float co_ = gl[(ch+98)*69 + p2]   + bb2[ch+98];
      float cg  = gl[(ch+147)*69 + p2]  + bb2[ch+147];
      float ig = 1.f/(1.f + __expf(-ci));
      float fg = 1.f/(1.f + __expf(-cf));
      float og = 1.f/(1.f + __expf(-co_));
      float g  = 1.f - 2.f/(__expf(2.f*cg) + 1.f);
      size_t e = ((size_t)b*49 + ch)*SS + pix;
      float cpv = cp[e];
      float cn = fg*cpv + ig*g;
      float hn = og * (1.f - 2.f/(__expf(2.f*cn) + 1.f));
      dout[cfg.h_off[lvl] + e] = hn;
      dout[cfg.c_off[lvl] + e] = cn;
    }
  }
}

// ---------------------------------------------------------------------------
extern "C" void kernel_launch(void* const* d_in, const int* in_sizes, int n_in,
                              void* d_out, int out_size, void* d_ws, size_t ws_size,
                              hipStream_t stream)
{
  const float *x[6], *xp[6], *h[6], *cpre[6], *w[6], *bias[6];
  for (int l = 0; l < 6; ++l) {
    x[l]    = (const float*)d_in[6*l + 0];
    xp[l]   = (const float*)d_in[6*l + 1];
    h[l]    = (const float*)d_in[6*l + 2];
    cpre[l] = (const float*)d_in[6*l + 3];
    w[l]    = (const float*)d_in[6*l + 4];
    bias[l] = (const float*)d_in[6*l + 5];
  }
  static const int SL[6] = {64,32,16,8,4,2};
  static const int CL[6] = {512,1024,512,256,256,256};
  int NSPL[6] = {8,16,16,1,1,1};

  long long hsz[6], lstm_off[6], h_off[6], poff[6];
  long long a1 = 0, a3 = 0;
  for (int l = 0; l < 6; ++l) {
    int S = SL[l], Sp = S + 2;
    hsz[l] = 8LL*49*S*S;
    lstm_off[l] = a1; a1 += 8LL*Sp*Sp*128;
    h_off[l]    = a3; a3 += hsz[l];
  }
  long long pa = 0;
  for (int l = 0; l < 6; ++l) { poff[l] = pa; pa += (long long)NSPL[l]*hsz[l]; }
  {
    long long need = a1*2 + 6LL*258048*2 + pa*2;
    if (need > (long long)ws_size) {      // fallback to smaller split config
      NSPL[0] = 4; NSPL[1] = 8; NSPL[2] = 16;
      pa = 0;
      for (int l = 0; l < 6; ++l) { poff[l] = pa; pa += (long long)NSPL[l]*hsz[l]; }
    }
  }
  const long long GRP = a3;            // floats per output group
  const long long LSTM_ELEMS = a1;     // bf16 elements

  uint16_t* lstm  = (uint16_t*)d_ws;
  uint16_t* wpack = (uint16_t*)((char*)d_ws + LSTM_ELEMS*2);
  _Float16* partial = (_Float16*)((char*)d_ws + LSTM_ELEMS*2 + 6LL*258048*2);
  float* dout = (float*)d_out;

  // corr (all levels, one launch)
  {
    CorrCfg ccfg;
    // big levels 0,1: 32x16 tiles -> l0: (64/16)*(64/32)=8 tiles, l1: 2 tiles
    static const int tpb2[2] = {8, 2};
    static const int txx2[2] = {2, 1};
    for (int l = 0; l < 6; ++l) { ccfg.gx[l] = x[l]; ccfg.gxp[l] = xp[l]; }
    int start = 0;
    for (int l = 0; l < 2; ++l) {
      ccfg.wg_start[l] = start;
      ccfg.S[l] = SL[l]; ccfg.C[l] = CL[l];
      ccfg.tiles_x[l] = txx2[l]; ccfg.tiles_pb[l] = tpb2[l];
      ccfg.cpl[l] = CL[l]/NSPL[l];
      ccfg.poff[l] = poff[l];
      start += NSPL[l]*8*tpb2[l];
    }
    ccfg.mid_start = start;
    ccfg.mcpl = CL[2]/NSPL[2];
    ccfg.mpoff = poff[2];
    start += NSPL[2]*8;
    for (int l = 0; l < 3; ++l) {
      ccfg.small_start[l] = start;
      ccfg.sS[l] = SL[l+3]; ccfg.sC[l] = CL[l+3];
      ccfg.sNspl[l] = NSPL[l+3];
      ccfg.spoff[l] = poff[l+3];
      start += (int)((NSPL[l+3]*hsz[l+3] + 255)/256);
    }
    corr_kernel<<<start, 256, 0, stream>>>(ccfg, partial);
  }
  // zero lstm_in (halo + channel pad), then weight pack
  (void)hipMemsetAsync(lstm, 0, (size_t)LSTM_ELEMS*2, stream);
  pack_w_kernel<<<6048, 256, 0, stream>>>(w[0],w[1],w[2],w[3],w[4],w[5], wpack);
  // pass2: partial sums -> leaky -> corr out + lstm_in (coalesced via LDS)
  {
    P2Cfg p2; int start = 0;
    static const int PXGL[6] = {64,64,64,64,16,4};
    static const int LGL[6]  = {6,6,6,6,4,2};
    for (int l = 0; l < 6; ++l) {
      p2.blk_start[l] = start;
      int gpb = (SL[l]*SL[l]) / PXGL[l]; if (gpb < 1) gpb = 1;
      p2.gpb[l] = gpb;
      start += 8 * gpb;
      p2.S[l] = SL[l]; p2.nsplit[l] = NSPL[l];
      p2.pxg[l] = PXGL[l]; p2.lg[l] = LGL[l];
      p2.poff[l] = poff[l]; p2.lstm_off[l] = lstm_off[l];
      p2.corr_off[l] = 2*GRP + h_off[l];
      p2.h[l] = h[l];
    }
    p2.blk_start[6] = start;
    pass2_kernel<<<start, 256, 0, stream>>>(p2, partial, (uint32_t*)lstm, dout);
  }
  // fused conv + gates (all levels, one launch)
  {
    CCfg cc;
    static const int ctpb[6] = {64, 16, 4, 1, 1, 1};
    static const int ctx[6]  = {4, 2, 1, 1, 1, 1};
    static const int clw[6]  = {4, 4, 4, 3, 2, 1};
    static const int cmfc[6] = {2, 2, 2, 2, 1, 1};
    static const int cmg[6]  = {2, 2, 2, 2, 1, 1};
    int start = 0;
    for (int l = 0; l < 6; ++l) {
      cc.wg_start[l] = start; start += 8*ctpb[l];
      cc.S[l] = SL[l]; cc.tiles_x[l] = ctx[l]; cc.tiles_pb[l] = ctpb[l];
      cc.lwsh[l] = clw[l]; cc.mfc[l] = cmfc[l]; cc.mgrp[l] = cmg[l];
      cc.lstm_off[l] = lstm_off[l];
      cc.wp_off[l] = 258048LL*l;
      cc.h_off[l] = h_off[l];
      cc.c_off[l] = GRP + h_off[l];
      cc.cpre[l] = cpre[l];
      cc.bias[l] = bias[l];
    }
    cc.wg_start[6] = start;
    conv_kernel<<<start, 256, 0, stream>>>(cc, lstm, wpack, dout);
  }
  (void)in_sizes; (void)n_in; (void)out_size; (void)ws_size;
}

// Round 8
// 469.164 us; speedup vs baseline: 1.1042x; 1.1042x over previous
//
#include <hip/hip_runtime.h>
#include <stdint.h>

#define DEV __device__ __forceinline__

typedef _Float16 half2_t __attribute__((ext_vector_type(2)));
typedef _Float16 half4_t __attribute__((ext_vector_type(4)));
typedef __bf16   bf16x8  __attribute__((ext_vector_type(8)));
typedef float    floatx4 __attribute__((ext_vector_type(4)));
typedef float    floatx2 __attribute__((ext_vector_type(2)));

DEV float fdot2f(half2_t a, half2_t b, float c) {
#if __has_builtin(__builtin_amdgcn_fdot2)
  return __builtin_amdgcn_fdot2(a, b, c, false);
#else
  return c + (float)a[0] * (float)b[0] + (float)a[1] * (float)b[1];
#endif
}

DEV half2_t pkh2(float a, float b) {
#if __has_builtin(__builtin_amdgcn_cvt_pkrtz)
  return __builtin_bit_cast(half2_t, __builtin_amdgcn_cvt_pkrtz(a, b));
#else
  half2_t r; r[0] = (_Float16)a; r[1] = (_Float16)b; return r;
#endif
}

DEV uint32_t f2bf(float f) {  // fp32 -> bf16 bits, RNE
  uint32_t u = __float_as_uint(f);
  return (u + 0x7FFFu + ((u >> 16) & 1u)) >> 16;
}

// Raw workgroup barrier: drains LDS ops only (lgkmcnt), NOT vmcnt.
// Global prefetch loads stay in flight across the barrier; their completion
// is enforced by normal register dependencies (at the f16 packs).
DEV void tile_barrier() {
  __builtin_amdgcn_sched_barrier(0);
  asm volatile("s_waitcnt lgkmcnt(0)" ::: "memory");
  __builtin_amdgcn_s_barrier();
  __builtin_amdgcn_sched_barrier(0);
}

// ---------------------------------------------------------------------------
// Correlation (all levels, one launch).
// Big levels (0,1): 32x16 px tile, 256 thr, 2 px/thread, conflict-free LDS
// (even stride 40, b64 window reads). Double-buffered staging (r5 structure,
// the measured-best) with BOTH staged operands packed to f16 at load:
// XP staging 8 half2 regs (was 16 fp32), X staging 8 half2 (was 16 fp32) —
// targets <=128 VGPR to cross the 2->4 waves/SIMD occupancy cliff (m69).
// Level 2: 16x16 1px/thread, same scheme. Small levels: 1 thr/output.
// ---------------------------------------------------------------------------
struct CorrCfg {
  const float* gx[6]; const float* gxp[6];
  int wg_start[2];     // big levels 0,1
  int mid_start;       // level 2
  int small_start[3];  // levels 3-5
  int S[2], C[2], tiles_x[2], tiles_pb[2], cpl[2];
  int mcpl;
  int sS[3], sC[3], sNspl[3];
  long long poff[2], mpoff, spoff[3];
};

__global__ __launch_bounds__(256)
void corr_kernel(CorrCfg cfg, _Float16* __restrict__ partial)
{
  __shared__ half2_t ldsbuf[2][2][22*40] __attribute__((aligned(16)));
  const int tid = threadIdx.x;
  int wg = blockIdx.x;

  if (wg >= cfg.small_start[0]) {
    // ---- small path (levels 3-5) ----
    int lvl = (wg >= cfg.small_start[2]) ? 2 : (wg >= cfg.small_start[1]) ? 1 : 0;
    long long i = (long long)(wg - cfg.small_start[lvl])*256 + tid;
    const int S = cfg.sS[lvl], C = cfg.sC[lvl], SS = S*S;
    const int nsp = cfg.sNspl[lvl];
    const long long per = (long long)8*49*SS;
    if (i >= (long long)nsp*per) return;
    int sp = (int)(i / per);
    long long rem = i - (long long)sp*per;
    const int cpl = C / nsp, cbase = sp * cpl;
    const float* X  = cfg.gx[lvl+3];
    const float* XP = cfg.gxp[lvl+3];
    int xc_ = (int)(rem % S); int yc = (int)((rem/S) % S);
    int d = (int)((rem/SS) % 49); int b = (int)(rem/((long long)49*SS));
    int yy = yc + d/7 - 3, xx = xc_ + (d%7) - 3;
    float s = 0.f;
    if (yy >= 0 && yy < S && xx >= 0 && xx < S) {
      const float* xb = X  + ((size_t)b*C + cbase)*SS + (size_t)yc*S + xc_;
      const float* pb = XP + ((size_t)b*C + cbase)*SS + (size_t)yy*S + xx;
      #pragma unroll 8
      for (int c = 0; c < cpl; ++c) s += xb[(size_t)c*SS] * pb[(size_t)c*SS];
    }
    partial[cfg.spoff[lvl] + (long long)sp*per + rem] = (_Float16)s;
    return;
  }

  if (wg >= cfg.mid_start) {
    // ---- mid path (level 2, S=16, C=512): 1 px/thread, b32 windows ----
    constexpr int NT = 256, MS = 16, MC = 512;
    constexpr int ROWS = 22, COLS = 22, ST = 23;
    constexpr int SLOTS = ROWS * 6 * 2;       // 264
    constexpr int PER = 2;
    int rel = wg - cfg.mid_start;
    const int cpl = cfg.mcpl;
    const int sp = rel >> 3;
    const int b = rel & 7;
    const int tx = tid & 15, ty = tid >> 4;
    const int cbase = sp * cpl;
    const size_t SS = (size_t)MS*MS;
    const float* Xb  = cfg.gx[2]  + (size_t)b*MC*SS;
    const float* XPb = cfg.gxp[2] + (size_t)b*MC*SS;
    const size_t qoff = (size_t)ty*MS + tx;

    int f_go[PER], f_base[PER], f_col0[PER], f_pr[PER];
    bool f_ok[PER], f_val[PER];
    #pragma unroll
    for (int s = 0; s < PER; ++s) {
      int i = tid + s*NT;
      bool val = (i < SLOTS);
      int ii = val ? i : 0;
      int pr = ii & 1;
      int rest = ii >> 1;
      int q = rest % 6;
      int r = rest / 6;
      int gy = r - 3;
      int gx0 = -4 + 4*q;
      bool ok = val && gy >= 0 && gy < MS && gx0 >= 0 && (gx0 + 3) < MS;
      f_val[s] = val; f_ok[s] = ok; f_pr[s] = pr;
      f_go[s] = ok ? gy*MS + gx0 : 0;
      f_col0[s] = 4*q - 1;
      f_base[s] = r*ST;
    }

    float acc[49];
    #pragma unroll
    for (int d = 0; d < 49; ++d) acc[d] = 0.f;
    half2_t pk[PER][4];         // XP staged, packed (ch pair per entry)
    half2_t xq0[2], xq1[2];     // X packed: [pr] = (c2pr, c2pr+1)

#define MFILL_LOADPK(c0v) { \
  _Pragma("unroll") for (int s = 0; s < PER; ++s) { \
    const float* p_ = XPb + (size_t)(cbase + (c0v) + 2*f_pr[s])*SS + f_go[s]; \
    floatx4 a_ = (floatx4)0.f, b2_ = (floatx4)0.f; \
    if (f_ok[s]) { a_ = *(const floatx4*)p_; b2_ = *(const floatx4*)(p_ + SS); } \
    _Pragma("unroll") for (int j = 0; j < 4; ++j) \
      pk[s][j] = pkh2(a_[j], b2_[j]); } }

#define MXLOADPK(dst, c0v) { \
  float t0_ = Xb[(size_t)(cbase + (c0v) + 0)*SS + qoff]; \
  float t1_ = Xb[(size_t)(cbase + (c0v) + 1)*SS + qoff]; \
  float t2_ = Xb[(size_t)(cbase + (c0v) + 2)*SS + qoff]; \
  float t3_ = Xb[(size_t)(cbase + (c0v) + 3)*SS + qoff]; \
  dst[0] = pkh2(t0_, t1_); dst[1] = pkh2(t2_, t3_); }

#define MFILL_STORE(bbv) { \
  _Pragma("unroll") for (int s = 0; s < PER; ++s) if (f_val[s]) { \
    half2_t* plane_ = &ldsbuf[bbv][f_pr[s]][0]; \
    _Pragma("unroll") for (int j = 0; j < 4; ++j) { \
      int col_ = f_col0[s] + j; \
      if (col_ >= 0 && col_ < COLS) \
        plane_[f_base[s] + col_] = pk[s][j]; } } }

#define MCOMPUTE(bbv, xq) { \
  _Pragma("unroll") for (int pr = 0; pr < 2; ++pr) { \
    half2_t xv = xq[pr]; \
    _Pragma("unroll") for (int di = 0; di < 7; ++di) { \
      const half2_t* row_ = &ldsbuf[bbv][pr][(ty+di)*ST + tx]; \
      _Pragma("unroll") for (int dj = 0; dj < 7; ++dj) \
        acc[di*7+dj] = fdot2f(xv, row_[dj], acc[di*7+dj]); } } }

    const int nchunk = cpl >> 2;
    MFILL_LOADPK(0); MXLOADPK(xq0, 0);
    MFILL_STORE(0);
    MFILL_LOADPK(4); MXLOADPK(xq1, 4);
    tile_barrier();
    for (int k = 0; k < nchunk; k += 2) {
      {
        if (k+1 < nchunk) MFILL_STORE(1);
        if (k+2 < nchunk) MFILL_LOADPK((k+2)*4);
        MCOMPUTE(0, xq0);
        if (k+2 < nchunk) MXLOADPK(xq0, (k+2)*4);
        tile_barrier();
      }
      if (k+1 < nchunk) {
        if (k+2 < nchunk) MFILL_STORE(0);
        if (k+3 < nchunk) MFILL_LOADPK((k+3)*4);
        MCOMPUTE(1, xq1);
        if (k+3 < nchunk) MXLOADPK(xq1, (k+3)*4);
        tile_barrier();
      }
    }
#undef MFILL_LOADPK
#undef MXLOADPK
#undef MFILL_STORE
#undef MCOMPUTE

    _Float16* P = partial + cfg.mpoff + ((size_t)sp*8 + b)*49*SS + qoff;
    #pragma unroll
    for (int d = 0; d < 49; ++d) P[(size_t)d*SS] = (_Float16)acc[d];
    return;
  }

  // ---- big path (levels 0,1): 32x16 tile, 2 px/thread, b64 windows ----
  {
    constexpr int NT = 256, TH = 16, TW = 32;
    constexpr int ROWS = TH + 6;            // 22
    constexpr int COLS = TW + 6;            // 38
    constexpr int QUADS = 10;
    constexpr int ST = TW + 8;              // 40 (even; bank-pair 20r+tx uniform)
    constexpr int SLOTS = ROWS * QUADS * 2; // 440
    constexpr int PER = 2;

    int lvl = (wg >= cfg.wg_start[1]) ? 1 : 0;
    wg -= cfg.wg_start[lvl];
    const float* X  = cfg.gx[lvl];
    const float* XP = cfg.gxp[lvl];
    const int S = cfg.S[lvl], C = cfg.C[lvl];
    const int txc = cfg.tiles_x[lvl], tpb = cfg.tiles_pb[lvl], cpl = cfg.cpl[lvl];
    const int per_split = 8 * tpb;
    const int sp = wg / per_split;
    const int rem = wg - sp*per_split;
    const int b = rem / tpb;
    const int t = rem - b*tpb;
    const int y0 = (t / txc) * TH, x0t = (t % txc) * TW;
    const int tx = tid & 15, ty = tid >> 4;
    const int cbase = sp * cpl;
    const size_t SS = (size_t)S*S;
    const float* Xb  = X  + (size_t)b*C*SS;
    const float* XPb = XP + (size_t)b*C*SS;
    const int py = y0 + ty, px = x0t + 2*tx;
    const size_t qoff = (size_t)py*S + px;

    int f_go[PER], f_base[PER], f_col0[PER], f_pr[PER];
    bool f_ok[PER], f_val[PER];
    #pragma unroll
    for (int s = 0; s < PER; ++s) {
      int i = tid + s*NT;
      bool val = (i < SLOTS);
      int ii = val ? i : 0;
      int pr = ii & 1;
      int rest = ii >> 1;
      int q = rest % QUADS;
      int r = rest / QUADS;
      int gy = y0 + r - 3;
      int gx0 = x0t - 4 + 4*q;
      bool ok = val && gy >= 0 && gy < S && gx0 >= 0 && (gx0 + 3) < S;
      f_val[s] = val; f_ok[s] = ok; f_pr[s] = pr;
      f_go[s] = ok ? gy*S + gx0 : 0;
      f_col0[s] = 4*q - 1;
      f_base[s] = r*ST;
    }

    floatx2 acc[49];
    #pragma unroll
    for (int d = 0; d < 49; ++d) acc[d] = (floatx2)0.f;
    half2_t pk[PER][4];          // XP staged, packed
    half2_t xq0[4], xq1[4];      // X packed: [2*pr+side], side: 0=px0, 1=px1

#define FILL_LOADPK(c0v) { \
  _Pragma("unroll") for (int s = 0; s < PER; ++s) { \
    const float* p_ = XPb + (size_t)(cbase + (c0v) + 2*f_pr[s])*SS + f_go[s]; \
    floatx4 a_ = (floatx4)0.f, b2_ = (floatx4)0.f; \
    if (f_ok[s]) { a_ = *(const floatx4*)p_; b2_ = *(const floatx4*)(p_ + SS); } \
    _Pragma("unroll") for (int j = 0; j < 4; ++j) \
      pk[s][j] = pkh2(a_[j], b2_[j]); } }

#define XLOADPK(dst, c0v) { \
  floatx2 t0_ = *(const floatx2*)(Xb + (size_t)(cbase + (c0v) + 0)*SS + qoff); \
  floatx2 t1_ = *(const floatx2*)(Xb + (size_t)(cbase + (c0v) + 1)*SS + qoff); \
  floatx2 t2_ = *(const floatx2*)(Xb + (size_t)(cbase + (c0v) + 2)*SS + qoff); \
  floatx2 t3_ = *(const floatx2*)(Xb + (size_t)(cbase + (c0v) + 3)*SS + qoff); \
  dst[0] = pkh2(t0_.x, t1_.x); dst[1] = pkh2(t0_.y, t1_.y); \
  dst[2] = pkh2(t2_.x, t3_.x); dst[3] = pkh2(t2_.y, t3_.y); }

#define FILL_STORE(bbv) { \
  _Pragma("unroll") for (int s = 0; s < PER; ++s) if (f_val[s]) { \
    half2_t* plane_ = &ldsbuf[bbv][f_pr[s]][0]; \
    _Pragma("unroll") for (int j = 0; j < 4; ++j) { \
      int col_ = f_col0[s] + j; \
      if (col_ >= 0 && col_ < COLS) \
        plane_[f_base[s] + col_] = pk[s][j]; } } }

#define COMPUTE(bbv, xq) { \
  _Pragma("unroll") for (int pr = 0; pr < 2; ++pr) { \
    half2_t xqa = xq[2*pr], xqb = xq[2*pr+1]; \
    _Pragma("unroll") for (int di = 0; di < 7; ++di) { \
      const half2_t* row_ = &ldsbuf[bbv][pr][(ty+di)*ST + 2*tx]; \
      half2_t L_[8]; \
      _Pragma("unroll") for (int k = 0; k < 4; ++k) { \
        half4_t v_ = *(const half4_t*)(row_ + 2*k); \
        L_[2*k]   = __builtin_shufflevector(v_, v_, 0, 1); \
        L_[2*k+1] = __builtin_shufflevector(v_, v_, 2, 3); } \
      _Pragma("unroll") for (int dj = 0; dj < 7; ++dj) { \
        acc[di*7+dj].x = fdot2f(xqa, L_[dj],   acc[di*7+dj].x); \
        acc[di*7+dj].y = fdot2f(xqb, L_[dj+1], acc[di*7+dj].y); } } } }

    const int nchunk = cpl >> 2;
    FILL_LOADPK(0); XLOADPK(xq0, 0);
    FILL_STORE(0);
    FILL_LOADPK(4); XLOADPK(xq1, 4);
    tile_barrier();
    for (int k = 0; k < nchunk; k += 2) {
      {
        if (k+1 < nchunk) FILL_STORE(1);
        if (k+2 < nchunk) FILL_LOADPK((k+2)*4);
        COMPUTE(0, xq0);
        if (k+2 < nchunk) XLOADPK(xq0, (k+2)*4);
        tile_barrier();
      }
      if (k+1 < nchunk) {
        if (k+2 < nchunk) FILL_STORE(0);
        if (k+3 < nchunk) FILL_LOADPK((k+3)*4);
        COMPUTE(1, xq1);
        if (k+3 < nchunk) XLOADPK(xq1, (k+3)*4);
        tile_barrier();
      }
    }
#undef FILL_LOADPK
#undef XLOADPK
#undef FILL_STORE
#undef COMPUTE

    _Float16* P = partial + cfg.poff[lvl] + ((size_t)sp*8 + b)*49*SS + qoff;
    #pragma unroll
    for (int d = 0; d < 49; ++d) {
      half2_t pko = pkh2(acc[d].x, acc[d].y);
      *(uint32_t*)(P + (size_t)d*SS) = *(const uint32_t*)&pko;
    }
  }
}

// ---------------------------------------------------------------------------
// Weight pack: w[196][98][3][3] fp32 -> bf16 MFMA B-fragments
// layout [lvl][t:14][s:36][lane:64][j:8], k = tap*128 + ch, N padded to 224.
// ---------------------------------------------------------------------------
__global__ __launch_bounds__(256)
void pack_w_kernel(const float* __restrict__ w0, const float* __restrict__ w1,
                   const float* __restrict__ w2, const float* __restrict__ w3,
                   const float* __restrict__ w4, const float* __restrict__ w5,
                   uint16_t* __restrict__ wpack)
{
  int idx = blockIdx.x*256 + threadIdx.x;
  int lvl = idx / 258048;
  int e = idx - lvl*258048;
  const float* W = lvl==0?w0:lvl==1?w1:lvl==2?w2:lvl==3?w3:lvl==4?w4:w5;
  int j = e & 7, lane = (e >> 3) & 63, rest = e >> 9;
  int s = rest % 36, tt = rest / 36;
  int n  = tt*16 + (lane & 15);
  int ch = (s & 3)*32 + (lane >> 4)*8 + j;
  int tap = s >> 2, ky = tap/3, kx = tap - 3*ky;
  float v = 0.f;
  if (n < 196 && ch < 98) v = W[((n*98 + ch)*3 + ky)*3 + kx];
  wpack[idx] = (uint16_t)f2bf(v);
}

// ---------------------------------------------------------------------------
// Pass2: block = (lvl, b, pixel-group). Stage A: coalesced gather of split
// partials (f16) -> fp32 sum -> leaky -> corr out (coalesced) + LDS[px][99];
// h gathered likewise. Stage B: wave-per-pixel packed bf16x2 u32 stores into
// channels-last lstm_in [b][y+1][x+1][128] (fully coalesced 256B/instr).
// ---------------------------------------------------------------------------
struct P2Cfg {
  int blk_start[7];
  int S[6], nsplit[6], pxg[6], lg[6], gpb[6];
  long long poff[6], lstm_off[6], corr_off[6];
  const float* h[6];
};
__global__ __launch_bounds__(256)
void pass2_kernel(P2Cfg cfg, const _Float16* __restrict__ partial,
                  uint32_t* __restrict__ lstm, float* __restrict__ dout)
{
  __shared__ float lds[64*99];
  int blk = blockIdx.x;
  int lvl = 0;
  while (lvl < 5 && blk >= cfg.blk_start[lvl+1]) ++lvl;
  int rel = blk - cfg.blk_start[lvl];
  const int S = cfg.S[lvl], Sp = S + 2, SS = S*S;
  const int PXG = cfg.pxg[lvl], lg = cfg.lg[lvl], gpb = cfg.gpb[lvl];
  const int b = rel / gpb, g = rel - b*gpb;
  const int pixbase = g * PXG;
  const int tid = threadIdx.x;
  const int nsp = cfg.nsplit[lvl];
  const size_t spstride = (size_t)8*49*SS;
  // stage A
  for (int e = tid; e < PXG*98; e += 256) {
    int pxl = e & (PXG-1);
    int ch  = e >> lg;
    int pix = pixbase + pxl;
    float v;
    if (ch < 49) {
      const _Float16* P = partial + cfg.poff[lvl] + ((size_t)b*49 + ch)*SS + pix;
      float s = 0.f;
      for (int sp = 0; sp < nsp; ++sp) s += (float)P[(size_t)sp*spstride];
      s = s < 0.f ? 0.01f*s : s;
      dout[cfg.corr_off[lvl] + ((size_t)b*49 + ch)*SS + pix] = s;
      v = s;
    } else {
      v = cfg.h[lvl][((size_t)b*49 + (ch - 49))*SS + pix];
    }
    lds[pxl*99 + ch] = v;
  }
  __syncthreads();
  // stage B
  uint32_t* Lb = lstm + (cfg.lstm_off[lvl] >> 1);
  for (int f = tid; f < (PXG << 6); f += 256) {
    int pxl = f >> 6, c2 = f & 63;
    int pix = pixbase + pxl;
    int y = pix / S, x = pix - y*S;
    int c0 = 2*c2, c1 = c0 + 1;
    float v0 = c0 < 98 ? lds[pxl*99 + c0] : 0.f;
    float v1 = c1 < 98 ? lds[pxl*99 + c1] : 0.f;
    Lb[((size_t)(b*Sp + y + 1)*Sp + (x + 1))*64 + c2] = f2bf(v0) | (f2bf(v1) << 16);
  }
}

// ---------------------------------------------------------------------------
// FUSED Conv 3x3 (98->196) + LSTM gates. Implicit GEMM, bf16 MFMA 16x16x32,
// K = 1152, N padded to 224; A direct from channels-last lstm_in, B packed.
// A conv block holds ALL 196 channels for its 64 pixels, so the gate math
// fuses here: acc -> LDS gl[n][69] (stride 69: store lanes spread ~all banks,
// gate reads p-consecutive = conflict-free) -> i,f,o,g -> h,c to dout.
// Eliminates the 137 MB convout write + 137 MB gate re-read + one launch.
// ---------------------------------------------------------------------------
struct CCfg {
  int wg_start[7];
  int S[6], tiles_x[6], tiles_pb[6], lwsh[6], mfc[6], mgrp[6];
  long long lstm_off[6], wp_off[6], h_off[6], c_off[6];
  const float* cpre[6]; const float* bias[6];
};
__global__ __launch_bounds__(256)
void conv_kernel(CCfg cfg, const uint16_t* __restrict__ lstm,
                 const uint16_t* __restrict__ wpack, float* __restrict__ dout)
{
  __shared__ float gl[224*69];   // [n][p] staging, 61.8 KB
  int wg = blockIdx.x;
  int lvl = 0;
  while (lvl < 5 && wg >= cfg.wg_start[lvl+1]) ++lvl;
  wg -= cfg.wg_start[lvl];
  const int S = cfg.S[lvl], Sp = S + 2;
  const int lwsh = cfg.lwsh[lvl], msk = (1 << lwsh) - 1;
  const int tpb = cfg.tiles_pb[lvl];
  const int b = wg / tpb, t = wg - b*tpb;
  const int ty0 = (t / cfg.tiles_x[lvl]) << (6 - lwsh);
  const int tx0 = (t % cfg.tiles_x[lvl]) << lwsh;
  const int tid = threadIdx.x;
  const int wave = tid >> 6, lane = tid & 63;
  const int nhalf = wave & 1, mhalf = wave >> 1;
  const int mfc = cfg.mfc[lvl];
  const bool active = (mhalf < cfg.mgrp[lvl]);
  const int mi = lane & 15, q = lane >> 4;
  const int SS = S*S;

  if (active) {
    const uint16_t* lb = lstm + cfg.lstm_off[lvl] + (size_t)b*Sp*Sp*128;
    int aoff[2];
    #pragma unroll
    for (int mf = 0; mf < 2; ++mf) {
      int p = mhalf*32 + mf*16 + mi;
      int pc = p < SS ? p : 0;                 // clamp (small-level pad)
      int y = ty0 + (pc >> lwsh), xx = tx0 + (pc & msk);
      aoff[mf] = (y*Sp + xx)*128 + q*8;
    }
    const uint16_t* wb = wpack + cfg.wp_off[lvl]
                       + (size_t)(nhalf*7)*36*512 + (size_t)lane*8;
    floatx4 acc[2][7];
    #pragma unroll
    for (int mf = 0; mf < 2; ++mf)
      #pragma unroll
      for (int nt = 0; nt < 7; ++nt) acc[mf][nt] = (floatx4)0.0f;

#define CONV_LOAD(sv, AV, BV) { \
  int tap_ = (sv) >> 2, cs_ = (sv) & 3; \
  int ky_ = tap_ / 3, kx_ = tap_ - 3*ky_; \
  int ao_ = ((ky_*Sp + kx_) << 7) + (cs_ << 5); \
  _Pragma("unroll") for (int mf = 0; mf < 2; ++mf) \
    if (mf < mfc) AV[mf] = *(const bf16x8*)(lb + aoff[mf] + ao_); \
  _Pragma("unroll") for (int nt = 0; nt < 7; ++nt) \
    BV[nt] = *(const bf16x8*)(wb + (size_t)((nt)*36 + (sv))*512); }

#define CONV_MFMA(AV, BV) { \
  _Pragma("unroll") for (int nt = 0; nt < 7; ++nt) \
    _Pragma("unroll") for (int mf = 0; mf < 2; ++mf) \
      if (mf < mfc) acc[mf][nt] = __builtin_amdgcn_mfma_f32_16x16x32_bf16( \
                        AV[mf], BV[nt], acc[mf][nt], 0, 0, 0); }

    bf16x8 av0[2], bv0[7], av1[2], bv1[7];
    CONV_LOAD(0, av0, bv0);
    for (int s = 0; s < 36; s += 2) {
      CONV_LOAD(s+1, av1, bv1);
      CONV_MFMA(av0, bv0);
      if (s+2 < 36) CONV_LOAD(s+2, av0, bv0);
      CONV_MFMA(av1, bv1);
    }
#undef CONV_LOAD
#undef CONV_MFMA

    // stage acc -> LDS [n][69]
    #pragma unroll
    for (int mf = 0; mf < 2; ++mf) {
      if (mf < mfc) {
        #pragma unroll
        for (int nt = 0; nt < 7; ++nt) {
          const int n = nhalf*112 + nt*16 + mi;
          if (n < 196) {
            #pragma unroll
            for (int r = 0; r < 4; ++r) {
              const int p = mhalf*32 + mf*16 + q*4 + r;
              gl[n*69 + p] = acc[mf][nt][r];
            }
          }
        }
      }
    }
  }
  __syncthreads();

  // gate phase: wave w handles unit-group w, lanes = pixels 0..63
  const int p2 = lane;           // pixel within tile
  const int grp = wave;          // 0..3 -> units 13,13,13,10
  if (p2 < SS) {
    const int y = ty0 + (p2 >> lwsh), xx = tx0 + (p2 & msk);
    const int pix = y*S + xx;
    const float* bb2 = cfg.bias[lvl];
    const float* cp  = cfg.cpre[lvl];
    const int ch0 = grp*13, chend = (grp == 3) ? 49 : grp*13 + 13;
    for (int ch = ch0; ch < chend; ++ch) {
      float ci  = gl[ch*69 + p2]        + bb2[ch];
      float cf  = gl[(ch+49)*69 + p2]   + bb2[ch+49];
      float co_ = gl[(ch+98)*69 + p2]   + bb2[ch+98];
      float cg  = gl[(ch+147)*69 + p2]  + bb2[ch+147];
      float ig = 1.f/(1.f + __expf(-ci));
      float fg = 1.f/(1.f + __expf(-cf));
      float og = 1.f/(1.f + __expf(-co_));
      float g  = 1.f - 2.f/(__expf(2.f*cg) + 1.f);
      size_t e = ((size_t)b*49 + ch)*SS + pix;
      float cpv = cp[e];
      float cn = fg*cpv + ig*g;
      float hn = og * (1.f - 2.f/(__expf(2.f*cn) + 1.f));
      dout[cfg.h_off[lvl] + e] = hn;
      dout[cfg.c_off[lvl] + e] = cn;
    }
  }
}

// ---------------------------------------------------------------------------
extern "C" void kernel_launch(void* const* d_in, const int* in_sizes, int n_in,
                              void* d_out, int out_size, void* d_ws, size_t ws_size,
                              hipStream_t stream)
{
  const float *x[6], *xp[6], *h[6], *cpre[6], *w[6], *bias[6];
  for (int l = 0; l < 6; ++l) {
    x[l]    = (const float*)d_in[6*l + 0];
    xp[l]   = (const float*)d_in[6*l + 1];
    h[l]    = (const float*)d_in[6*l + 2];
    cpre[l] = (const float*)d_in[6*l + 3];
    w[l]    = (const float*)d_in[6*l + 4];
    bias[l] = (const float*)d_in[6*l + 5];
  }
  static const int SL[6] = {64,32,16,8,4,2};
  static const int CL[6] = {512,1024,512,256,256,256};
  int NSPL[6] = {8,16,16,1,1,1};

  long long hsz[6], lstm_off[6], h_off[6], poff[6];
  long long a1 = 0, a3 = 0;
  for (int l = 0; l < 6; ++l) {
    int S = SL[l], Sp = S + 2;
    hsz[l] = 8LL*49*S*S;
    lstm_off[l] = a1; a1 += 8LL*Sp*Sp*128;
    h_off[l]    = a3; a3 += hsz[l];
  }
  long long pa = 0;
  for (int l = 0; l < 6; ++l) { poff[l] = pa; pa += (long long)NSPL[l]*hsz[l]; }
  {
    long long need = a1*2 + 6LL*258048*2 + pa*2;
    if (need > (long long)ws_size) {      // fallback to smaller split config
      NSPL[0] = 4; NSPL[1] = 8; NSPL[2] = 16;
      pa = 0;
      for (int l = 0; l < 6; ++l) { poff[l] = pa; pa += (long long)NSPL[l]*hsz[l]; }
    }
  }
  const long long GRP = a3;            // floats per output group
  const long long LSTM_ELEMS = a1;     // bf16 elements

  uint16_t* lstm  = (uint16_t*)d_ws;
  uint16_t* wpack = (uint16_t*)((char*)d_ws + LSTM_ELEMS*2);
  _Float16* partial = (_Float16*)((char*)d_ws + LSTM_ELEMS*2 + 6LL*258048*2);
  float* dout = (float*)d_out;

  // corr (all levels, one launch)
  {
    CorrCfg ccfg;
    // big levels 0,1: 32x16 tiles -> l0: (64/16)*(64/32)=8 tiles, l1: 2 tiles
    static const int tpb2[2] = {8, 2};
    static const int txx2[2] = {2, 1};
    for (int l = 0; l < 6; ++l) { ccfg.gx[l] = x[l]; ccfg.gxp[l] = xp[l]; }
    int start = 0;
    for (int l = 0; l < 2; ++l) {
      ccfg.wg_start[l] = start;
      ccfg.S[l] = SL[l]; ccfg.C[l] = CL[l];
      ccfg.tiles_x[l] = txx2[l]; ccfg.tiles_pb[l] = tpb2[l];
      ccfg.cpl[l] = CL[l]/NSPL[l];
      ccfg.poff[l] = poff[l];
      start += NSPL[l]*8*tpb2[l];
    }
    ccfg.mid_start = start;
    ccfg.mcpl = CL[2]/NSPL[2];
    ccfg.mpoff = poff[2];
    start += NSPL[2]*8;
    for (int l = 0; l < 3; ++l) {
      ccfg.small_start[l] = start;
      ccfg.sS[l] = SL[l+3]; ccfg.sC[l] = CL[l+3];
      ccfg.sNspl[l] = NSPL[l+3];
      ccfg.spoff[l] = poff[l+3];
      start += (int)((NSPL[l+3]*hsz[l+3] + 255)/256);
    }
    corr_kernel<<<start, 256, 0, stream>>>(ccfg, partial);
  }
  // zero lstm_in (halo + channel pad), then weight pack
  (void)hipMemsetAsync(lstm, 0, (size_t)LSTM_ELEMS*2, stream);
  pack_w_kernel<<<6048, 256, 0, stream>>>(w[0],w[1],w[2],w[3],w[4],w[5], wpack);
  // pass2: partial sums -> leaky -> corr out + lstm_in (coalesced via LDS)
  {
    P2Cfg p2; int start = 0;
    static const int PXGL[6] = {64,64,64,64,16,4};
    static const int LGL[6]  = {6,6,6,6,4,2};
    for (int l = 0; l < 6; ++l) {
      p2.blk_start[l] = start;
      int gpb = (SL[l]*SL[l]) / PXGL[l]; if (gpb < 1) gpb = 1;
      p2.gpb[l] = gpb;
      start += 8 * gpb;
      p2.S[l] = SL[l]; p2.nsplit[l] = NSPL[l];
      p2.pxg[l] = PXGL[l]; p2.lg[l] = LGL[l];
      p2.poff[l] = poff[l]; p2.lstm_off[l] = lstm_off[l];
      p2.corr_off[l] = 2*GRP + h_off[l];
      p2.h[l] = h[l];
    }
    p2.blk_start[6] = start;
    pass2_kernel<<<start, 256, 0, stream>>>(p2, partial, (uint32_t*)lstm, dout);
  }
  // fused conv + gates (all levels, one launch)
  {
    CCfg cc;
    static const int ctpb[6] = {64, 16, 4, 1, 1, 1};
    static const int ctx[6]  = {4, 2, 1, 1, 1, 1};
    static const int clw[6]  = {4, 4, 4, 3, 2, 1};
    static const int cmfc[6] = {2, 2, 2, 2, 1, 1};
    static const int cmg[6]  = {2, 2, 2, 2, 1, 1};
    int start = 0;
    for (int l = 0; l < 6; ++l) {
      cc.wg_start[l] = start; start += 8*ctpb[l];
      cc.S[l] = SL[l]; cc.tiles_x[l] = ctx[l]; cc.tiles_pb[l] = ctpb[l];
      cc.lwsh[l] = clw[l]; cc.mfc[l] = cmfc[l]; cc.mgrp[l] = cmg[l];
      cc.lstm_off[l] = lstm_off[l];
      cc.wp_off[l] = 258048LL*l;
      cc.h_off[l] = h_off[l];
      cc.c_off[l] = GRP + h_off[l];
      cc.cpre[l] = cpre[l];
      cc.bias[l] = bias[l];
    }
    cc.wg_start[6] = start;
    conv_kernel<<<start, 256, 0, stream>>>(cc, lstm, wpack, dout);
  }
  (void)in_sizes; (void)n_in; (void)out_size; (void)ws_size;
}

// Round 9
// 434.569 us; speedup vs baseline: 1.1920x; 1.0796x over previous
//
#include <hip/hip_runtime.h>
#include <stdint.h>

#define DEV __device__ __forceinline__

typedef _Float16 half2_t __attribute__((ext_vector_type(2)));
typedef _Float16 half4_t __attribute__((ext_vector_type(4)));
typedef __bf16   bf16x8  __attribute__((ext_vector_type(8)));
typedef float    floatx4 __attribute__((ext_vector_type(4)));
typedef float    floatx2 __attribute__((ext_vector_type(2)));

DEV float fdot2f(half2_t a, half2_t b, float c) {
#if __has_builtin(__builtin_amdgcn_fdot2)
  return __builtin_amdgcn_fdot2(a, b, c, false);
#else
  return c + (float)a[0] * (float)b[0] + (float)a[1] * (float)b[1];
#endif
}

DEV half2_t pkh2(float a, float b) {
#if __has_builtin(__builtin_amdgcn_cvt_pkrtz)
  return __builtin_bit_cast(half2_t, __builtin_amdgcn_cvt_pkrtz(a, b));
#else
  half2_t r; r[0] = (_Float16)a; r[1] = (_Float16)b; return r;
#endif
}

DEV uint32_t f2bf(float f) {  // fp32 -> bf16 bits, RNE
  uint32_t u = __float_as_uint(f);
  return (u + 0x7FFFu + ((u >> 16) & 1u)) >> 16;
}

// Raw workgroup barrier: drains LDS ops only (lgkmcnt), NOT vmcnt.
// Global prefetch loads stay in flight across the barrier; their completion
// is enforced by normal register dependencies (at the f16 packs).
DEV void tile_barrier() {
  __builtin_amdgcn_sched_barrier(0);
  asm volatile("s_waitcnt lgkmcnt(0)" ::: "memory");
  __builtin_amdgcn_s_barrier();
  __builtin_amdgcn_sched_barrier(0);
}

// ---------------------------------------------------------------------------
// Correlation (all levels, one launch).  [UNCHANGED from round 8 — proven:
// 114 µs, VGPR=128 = 4 waves/SIMD, grid ~4 blocks/CU fills the VGPR pool.]
// ---------------------------------------------------------------------------
struct CorrCfg {
  const float* gx[6]; const float* gxp[6];
  int wg_start[2];     // big levels 0,1
  int mid_start;       // level 2
  int small_start[3];  // levels 3-5
  int S[2], C[2], tiles_x[2], tiles_pb[2], cpl[2];
  int mcpl;
  int sS[3], sC[3], sNspl[3];
  long long poff[2], mpoff, spoff[3];
};

__global__ __launch_bounds__(256)
void corr_kernel(CorrCfg cfg, _Float16* __restrict__ partial)
{
  __shared__ half2_t ldsbuf[2][2][22*40] __attribute__((aligned(16)));
  const int tid = threadIdx.x;
  int wg = blockIdx.x;

  if (wg >= cfg.small_start[0]) {
    // ---- small path (levels 3-5) ----
    int lvl = (wg >= cfg.small_start[2]) ? 2 : (wg >= cfg.small_start[1]) ? 1 : 0;
    long long i = (long long)(wg - cfg.small_start[lvl])*256 + tid;
    const int S = cfg.sS[lvl], C = cfg.sC[lvl], SS = S*S;
    const int nsp = cfg.sNspl[lvl];
    const long long per = (long long)8*49*SS;
    if (i >= (long long)nsp*per) return;
    int sp = (int)(i / per);
    long long rem = i - (long long)sp*per;
    const int cpl = C / nsp, cbase = sp * cpl;
    const float* X  = cfg.gx[lvl+3];
    const float* XP = cfg.gxp[lvl+3];
    int xc_ = (int)(rem % S); int yc = (int)((rem/S) % S);
    int d = (int)((rem/SS) % 49); int b = (int)(rem/((long long)49*SS));
    int yy = yc + d/7 - 3, xx = xc_ + (d%7) - 3;
    float s = 0.f;
    if (yy >= 0 && yy < S && xx >= 0 && xx < S) {
      const float* xb = X  + ((size_t)b*C + cbase)*SS + (size_t)yc*S + xc_;
      const float* pb = XP + ((size_t)b*C + cbase)*SS + (size_t)yy*S + xx;
      #pragma unroll 8
      for (int c = 0; c < cpl; ++c) s += xb[(size_t)c*SS] * pb[(size_t)c*SS];
    }
    partial[cfg.spoff[lvl] + (long long)sp*per + rem] = (_Float16)s;
    return;
  }

  if (wg >= cfg.mid_start) {
    // ---- mid path (level 2, S=16, C=512): 1 px/thread, b32 windows ----
    constexpr int NT = 256, MS = 16, MC = 512;
    constexpr int ROWS = 22, COLS = 22, ST = 23;
    constexpr int SLOTS = ROWS * 6 * 2;       // 264
    constexpr int PER = 2;
    int rel = wg - cfg.mid_start;
    const int cpl = cfg.mcpl;
    const int sp = rel >> 3;
    const int b = rel & 7;
    const int tx = tid & 15, ty = tid >> 4;
    const int cbase = sp * cpl;
    const size_t SS = (size_t)MS*MS;
    const float* Xb  = cfg.gx[2]  + (size_t)b*MC*SS;
    const float* XPb = cfg.gxp[2] + (size_t)b*MC*SS;
    const size_t qoff = (size_t)ty*MS + tx;

    int f_go[PER], f_base[PER], f_col0[PER], f_pr[PER];
    bool f_ok[PER], f_val[PER];
    #pragma unroll
    for (int s = 0; s < PER; ++s) {
      int i = tid + s*NT;
      bool val = (i < SLOTS);
      int ii = val ? i : 0;
      int pr = ii & 1;
      int rest = ii >> 1;
      int q = rest % 6;
      int r = rest / 6;
      int gy = r - 3;
      int gx0 = -4 + 4*q;
      bool ok = val && gy >= 0 && gy < MS && gx0 >= 0 && (gx0 + 3) < MS;
      f_val[s] = val; f_ok[s] = ok; f_pr[s] = pr;
      f_go[s] = ok ? gy*MS + gx0 : 0;
      f_col0[s] = 4*q - 1;
      f_base[s] = r*ST;
    }

    float acc[49];
    #pragma unroll
    for (int d = 0; d < 49; ++d) acc[d] = 0.f;
    half2_t pk[PER][4];         // XP staged, packed (ch pair per entry)
    half2_t xq0[2], xq1[2];     // X packed: [pr] = (c2pr, c2pr+1)

#define MFILL_LOADPK(c0v) { \
  _Pragma("unroll") for (int s = 0; s < PER; ++s) { \
    const float* p_ = XPb + (size_t)(cbase + (c0v) + 2*f_pr[s])*SS + f_go[s]; \
    floatx4 a_ = (floatx4)0.f, b2_ = (floatx4)0.f; \
    if (f_ok[s]) { a_ = *(const floatx4*)p_; b2_ = *(const floatx4*)(p_ + SS); } \
    _Pragma("unroll") for (int j = 0; j < 4; ++j) \
      pk[s][j] = pkh2(a_[j], b2_[j]); } }

#define MXLOADPK(dst, c0v) { \
  float t0_ = Xb[(size_t)(cbase + (c0v) + 0)*SS + qoff]; \
  float t1_ = Xb[(size_t)(cbase + (c0v) + 1)*SS + qoff]; \
  float t2_ = Xb[(size_t)(cbase + (c0v) + 2)*SS + qoff]; \
  float t3_ = Xb[(size_t)(cbase + (c0v) + 3)*SS + qoff]; \
  dst[0] = pkh2(t0_, t1_); dst[1] = pkh2(t2_, t3_); }

#define MFILL_STORE(bbv) { \
  _Pragma("unroll") for (int s = 0; s < PER; ++s) if (f_val[s]) { \
    half2_t* plane_ = &ldsbuf[bbv][f_pr[s]][0]; \
    _Pragma("unroll") for (int j = 0; j < 4; ++j) { \
      int col_ = f_col0[s] + j; \
      if (col_ >= 0 && col_ < COLS) \
        plane_[f_base[s] + col_] = pk[s][j]; } } }

#define MCOMPUTE(bbv, xq) { \
  _Pragma("unroll") for (int pr = 0; pr < 2; ++pr) { \
    half2_t xv = xq[pr]; \
    _Pragma("unroll") for (int di = 0; di < 7; ++di) { \
      const half2_t* row_ = &ldsbuf[bbv][pr][(ty+di)*ST + tx]; \
      _Pragma("unroll") for (int dj = 0; dj < 7; ++dj) \
        acc[di*7+dj] = fdot2f(xv, row_[dj], acc[di*7+dj]); } } }

    const int nchunk = cpl >> 2;
    MFILL_LOADPK(0); MXLOADPK(xq0, 0);
    MFILL_STORE(0);
    MFILL_LOADPK(4); MXLOADPK(xq1, 4);
    tile_barrier();
    for (int k = 0; k < nchunk; k += 2) {
      {
        if (k+1 < nchunk) MFILL_STORE(1);
        if (k+2 < nchunk) MFILL_LOADPK((k+2)*4);
        MCOMPUTE(0, xq0);
        if (k+2 < nchunk) MXLOADPK(xq0, (k+2)*4);
        tile_barrier();
      }
      if (k+1 < nchunk) {
        if (k+2 < nchunk) MFILL_STORE(0);
        if (k+3 < nchunk) MFILL_LOADPK((k+3)*4);
        MCOMPUTE(1, xq1);
        if (k+3 < nchunk) MXLOADPK(xq1, (k+3)*4);
        tile_barrier();
      }
    }
#undef MFILL_LOADPK
#undef MXLOADPK
#undef MFILL_STORE
#undef MCOMPUTE

    _Float16* P = partial + cfg.mpoff + ((size_t)sp*8 + b)*49*SS + qoff;
    #pragma unroll
    for (int d = 0; d < 49; ++d) P[(size_t)d*SS] = (_Float16)acc[d];
    return;
  }

  // ---- big path (levels 0,1): 32x16 tile, 2 px/thread, b64 windows ----
  {
    constexpr int NT = 256, TH = 16, TW = 32;
    constexpr int ROWS = TH + 6;            // 22
    constexpr int COLS = TW + 6;            // 38
    constexpr int QUADS = 10;
    constexpr int ST = TW + 8;              // 40 (even; bank-pair 20r+tx uniform)
    constexpr int SLOTS = ROWS * QUADS * 2; // 440
    constexpr int PER = 2;

    int lvl = (wg >= cfg.wg_start[1]) ? 1 : 0;
    wg -= cfg.wg_start[lvl];
    const float* X  = cfg.gx[lvl];
    const float* XP = cfg.gxp[lvl];
    const int S = cfg.S[lvl], C = cfg.C[lvl];
    const int txc = cfg.tiles_x[lvl], tpb = cfg.tiles_pb[lvl], cpl = cfg.cpl[lvl];
    const int per_split = 8 * tpb;
    const int sp = wg / per_split;
    const int rem = wg - sp*per_split;
    const int b = rem / tpb;
    const int t = rem - b*tpb;
    const int y0 = (t / txc) * TH, x0t = (t % txc) * TW;
    const int tx = tid & 15, ty = tid >> 4;
    const int cbase = sp * cpl;
    const size_t SS = (size_t)S*S;
    const float* Xb  = X  + (size_t)b*C*SS;
    const float* XPb = XP + (size_t)b*C*SS;
    const int py = y0 + ty, px = x0t + 2*tx;
    const size_t qoff = (size_t)py*S + px;

    int f_go[PER], f_base[PER], f_col0[PER], f_pr[PER];
    bool f_ok[PER], f_val[PER];
    #pragma unroll
    for (int s = 0; s < PER; ++s) {
      int i = tid + s*NT;
      bool val = (i < SLOTS);
      int ii = val ? i : 0;
      int pr = ii & 1;
      int rest = ii >> 1;
      int q = rest % QUADS;
      int r = rest / QUADS;
      int gy = y0 + r - 3;
      int gx0 = x0t - 4 + 4*q;
      bool ok = val && gy >= 0 && gy < S && gx0 >= 0 && (gx0 + 3) < S;
      f_val[s] = val; f_ok[s] = ok; f_pr[s] = pr;
      f_go[s] = ok ? gy*S + gx0 : 0;
      f_col0[s] = 4*q - 1;
      f_base[s] = r*ST;
    }

    floatx2 acc[49];
    #pragma unroll
    for (int d = 0; d < 49; ++d) acc[d] = (floatx2)0.f;
    half2_t pk[PER][4];          // XP staged, packed
    half2_t xq0[4], xq1[4];      // X packed: [2*pr+side], side: 0=px0, 1=px1

#define FILL_LOADPK(c0v) { \
  _Pragma("unroll") for (int s = 0; s < PER; ++s) { \
    const float* p_ = XPb + (size_t)(cbase + (c0v) + 2*f_pr[s])*SS + f_go[s]; \
    floatx4 a_ = (floatx4)0.f, b2_ = (floatx4)0.f; \
    if (f_ok[s]) { a_ = *(const floatx4*)p_; b2_ = *(const floatx4*)(p_ + SS); } \
    _Pragma("unroll") for (int j = 0; j < 4; ++j) \
      pk[s][j] = pkh2(a_[j], b2_[j]); } }

#define XLOADPK(dst, c0v) { \
  floatx2 t0_ = *(const floatx2*)(Xb + (size_t)(cbase + (c0v) + 0)*SS + qoff); \
  floatx2 t1_ = *(const floatx2*)(Xb + (size_t)(cbase + (c0v) + 1)*SS + qoff); \
  floatx2 t2_ = *(const floatx2*)(Xb + (size_t)(cbase + (c0v) + 2)*SS + qoff); \
  floatx2 t3_ = *(const floatx2*)(Xb + (size_t)(cbase + (c0v) + 3)*SS + qoff); \
  dst[0] = pkh2(t0_.x, t1_.x); dst[1] = pkh2(t0_.y, t1_.y); \
  dst[2] = pkh2(t2_.x, t3_.x); dst[3] = pkh2(t2_.y, t3_.y); }

#define FILL_STORE(bbv) { \
  _Pragma("unroll") for (int s = 0; s < PER; ++s) if (f_val[s]) { \
    half2_t* plane_ = &ldsbuf[bbv][f_pr[s]][0]; \
    _Pragma("unroll") for (int j = 0; j < 4; ++j) { \
      int col_ = f_col0[s] + j; \
      if (col_ >= 0 && col_ < COLS) \
        plane_[f_base[s] + col_] = pk[s][j]; } } }

#define COMPUTE(bbv, xq) { \
  _Pragma("unroll") for (int pr = 0; pr < 2; ++pr) { \
    half2_t xqa = xq[2*pr], xqb = xq[2*pr+1]; \
    _Pragma("unroll") for (int di = 0; di < 7; ++di) { \
      const half2_t* row_ = &ldsbuf[bbv][pr][(ty+di)*ST + 2*tx]; \
      half2_t L_[8]; \
      _Pragma("unroll") for (int k = 0; k < 4; ++k) { \
        half4_t v_ = *(const half4_t*)(row_ + 2*k); \
        L_[2*k]   = __builtin_shufflevector(v_, v_, 0, 1); \
        L_[2*k+1] = __builtin_shufflevector(v_, v_, 2, 3); } \
      _Pragma("unroll") for (int dj = 0; dj < 7; ++dj) { \
        acc[di*7+dj].x = fdot2f(xqa, L_[dj],   acc[di*7+dj].x); \
        acc[di*7+dj].y = fdot2f(xqb, L_[dj+1], acc[di*7+dj].y); } } } }

    const int nchunk = cpl >> 2;
    FILL_LOADPK(0); XLOADPK(xq0, 0);
    FILL_STORE(0);
    FILL_LOADPK(4); XLOADPK(xq1, 4);
    tile_barrier();
    for (int k = 0; k < nchunk; k += 2) {
      {
        if (k+1 < nchunk) FILL_STORE(1);
        if (k+2 < nchunk) FILL_LOADPK((k+2)*4);
        COMPUTE(0, xq0);
        if (k+2 < nchunk) XLOADPK(xq0, (k+2)*4);
        tile_barrier();
      }
      if (k+1 < nchunk) {
        if (k+2 < nchunk) FILL_STORE(0);
        if (k+3 < nchunk) FILL_LOADPK((k+3)*4);
        COMPUTE(1, xq1);
        if (k+3 < nchunk) XLOADPK(xq1, (k+3)*4);
        tile_barrier();
      }
    }
#undef FILL_LOADPK
#undef XLOADPK
#undef FILL_STORE
#undef COMPUTE

    _Float16* P = partial + cfg.poff[lvl] + ((size_t)sp*8 + b)*49*SS + qoff;
    #pragma unroll
    for (int d = 0; d < 49; ++d) {
      half2_t pko = pkh2(acc[d].x, acc[d].y);
      *(uint32_t*)(P + (size_t)d*SS) = *(const uint32_t*)&pko;
    }
  }
}

// ---------------------------------------------------------------------------
// Weight pack: w[196][98][3][3] fp32 -> bf16 MFMA B-fragments
// layout [lvl][t:14][s:36][lane:64][j:8], k = tap*128 + ch, N padded to 224.
// ---------------------------------------------------------------------------
__global__ __launch_bounds__(256)
void pack_w_kernel(const float* __restrict__ w0, const float* __restrict__ w1,
                   const float* __restrict__ w2, const float* __restrict__ w3,
                   const float* __restrict__ w4, const float* __restrict__ w5,
                   uint16_t* __restrict__ wpack)
{
  int idx = blockIdx.x*256 + threadIdx.x;
  int lvl = idx / 258048;
  int e = idx - lvl*258048;
  const float* W = lvl==0?w0:lvl==1?w1:lvl==2?w2:lvl==3?w3:lvl==4?w4:w5;
  int j = e & 7, lane = (e >> 3) & 63, rest = e >> 9;
  int s = rest % 36, tt = rest / 36;
  int n  = tt*16 + (lane & 15);
  int ch = (s & 3)*32 + (lane >> 4)*8 + j;
  int tap = s >> 2, ky = tap/3, kx = tap - 3*ky;
  float v = 0.f;
  if (n < 196 && ch < 98) v = W[((n*98 + ch)*3 + ky)*3 + kx];
  wpack[idx] = (uint16_t)f2bf(v);
}

// ---------------------------------------------------------------------------
// Pass2: block = (lvl, b, pixel-group). Stage A VECTORIZED: 4 px/thread —
// each split read is one half4 (8 B/lane = 512 B/wave-instr, was 2 B scalar),
// leaky + corr-out float4 store, h float4 load (SS & pix are multiples of 4,
// all bases 16B-aligned). L0 PXG 64->32 doubles its block count (1024) for
// latency cover. Stage B unchanged (packed bf16x2 u32 stores, coalesced).
// ---------------------------------------------------------------------------
struct P2Cfg {
  int blk_start[7];
  int S[6], nsplit[6], pxg[6], lg[6], gpb[6];
  long long poff[6], lstm_off[6], corr_off[6];
  const float* h[6];
};
__global__ __launch_bounds__(256)
void pass2_kernel(P2Cfg cfg, const _Float16* __restrict__ partial,
                  uint32_t* __restrict__ lstm, float* __restrict__ dout)
{
  __shared__ float lds[64*99];
  int blk = blockIdx.x;
  int lvl = 0;
  while (lvl < 5 && blk >= cfg.blk_start[lvl+1]) ++lvl;
  int rel = blk - cfg.blk_start[lvl];
  const int S = cfg.S[lvl], Sp = S + 2, SS = S*S;
  const int PXG = cfg.pxg[lvl], lg = cfg.lg[lvl], gpb = cfg.gpb[lvl];
  const int b = rel / gpb, g = rel - b*gpb;
  const int pixbase = g * PXG;
  const int tid = threadIdx.x;
  const int nsp = cfg.nsplit[lvl];
  const size_t spstride = (size_t)8*49*SS;
  // stage A: 4 px per thread
  const int quads = PXG >> 2;
  const int lq = lg - 2;
  for (int e = tid; e < quads*98; e += 256) {
    int qx = e & (quads - 1);
    int ch = e >> lq;
    int pix = pixbase + 4*qx;
    floatx4 v;
    if (ch < 49) {
      const _Float16* P = partial + cfg.poff[lvl] + ((size_t)b*49 + ch)*SS + pix;
      floatx4 s = (floatx4)0.f;
      for (int sp = 0; sp < nsp; ++sp) {
        half4_t pv = *(const half4_t*)(P + (size_t)sp*spstride);
        s[0] += (float)pv[0]; s[1] += (float)pv[1];
        s[2] += (float)pv[2]; s[3] += (float)pv[3];
      }
      #pragma unroll
      for (int j = 0; j < 4; ++j) s[j] = s[j] < 0.f ? 0.01f*s[j] : s[j];
      *(floatx4*)(dout + cfg.corr_off[lvl] + ((size_t)b*49 + ch)*SS + pix) = s;
      v = s;
    } else {
      v = *(const floatx4*)(cfg.h[lvl] + ((size_t)b*49 + (ch - 49))*SS + pix);
    }
    int pxl = 4*qx;
    lds[(pxl+0)*99 + ch] = v[0];
    lds[(pxl+1)*99 + ch] = v[1];
    lds[(pxl+2)*99 + ch] = v[2];
    lds[(pxl+3)*99 + ch] = v[3];
  }
  __syncthreads();
  // stage B
  uint32_t* Lb = lstm + (cfg.lstm_off[lvl] >> 1);
  for (int f = tid; f < (PXG << 6); f += 256) {
    int pxl = f >> 6, c2 = f & 63;
    int pix = pixbase + pxl;
    int y = pix / S, x = pix - y*S;
    int c0 = 2*c2, c1 = c0 + 1;
    float v0 = c0 < 98 ? lds[pxl*99 + c0] : 0.f;
    float v1 = c1 < 98 ? lds[pxl*99 + c1] : 0.f;
    Lb[((size_t)(b*Sp + y + 1)*Sp + (x + 1))*64 + c2] = f2bf(v0) | (f2bf(v1) << 16);
  }
}

// ---------------------------------------------------------------------------
// FUSED Conv 3x3 (98->196) + LSTM gates.  [UNCHANGED from round 8]
// ---------------------------------------------------------------------------
struct CCfg {
  int wg_start[7];
  int S[6], tiles_x[6], tiles_pb[6], lwsh[6], mfc[6], mgrp[6];
  long long lstm_off[6], wp_off[6], h_off[6], c_off[6];
  const float* cpre[6]; const float* bias[6];
};
__global__ __launch_bounds__(256)
void conv_kernel(CCfg cfg, const uint16_t* __restrict__ lstm,
                 const uint16_t* __restrict__ wpack, float* __restrict__ dout)
{
  __shared__ float gl[224*69];   // [n][p] staging, 61.8 KB
  int wg = blockIdx.x;
  int lvl = 0;
  while (lvl < 5 && wg >= cfg.wg_start[lvl+1]) ++lvl;
  wg -= cfg.wg_start[lvl];
  const int S = cfg.S[lvl], Sp = S + 2;
  const int lwsh = cfg.lwsh[lvl], msk = (1 << lwsh) - 1;
  const int tpb = cfg.tiles_pb[lvl];
  const int b = wg / tpb, t = wg - b*tpb;
  const int ty0 = (t / cfg.tiles_x[lvl]) << (6 - lwsh);
  const int tx0 = (t % cfg.tiles_x[lvl]) << lwsh;
  const int tid = threadIdx.x;
  const int wave = tid >> 6, lane = tid & 63;
  const int nhalf = wave & 1, mhalf = wave >> 1;
  const int mfc = cfg.mfc[lvl];
  const bool active = (mhalf < cfg.mgrp[lvl]);
  const int mi = lane & 15, q = lane >> 4;
  const int SS = S*S;

  if (active) {
    const uint16_t* lb = lstm + cfg.lstm_off[lvl] + (size_t)b*Sp*Sp*128;
    int aoff[2];
    #pragma unroll
    for (int mf = 0; mf < 2; ++mf) {
      int p = mhalf*32 + mf*16 + mi;
      int pc = p < SS ? p : 0;                 // clamp (small-level pad)
      int y = ty0 + (pc >> lwsh), xx = tx0 + (pc & msk);
      aoff[mf] = (y*Sp + xx)*128 + q*8;
    }
    const uint16_t* wb = wpack + cfg.wp_off[lvl]
                       + (size_t)(nhalf*7)*36*512 + (size_t)lane*8;
    floatx4 acc[2][7];
    #pragma unroll
    for (int mf = 0; mf < 2; ++mf)
      #pragma unroll
      for (int nt = 0; nt < 7; ++nt) acc[mf][nt] = (floatx4)0.0f;

#define CONV_LOAD(sv, AV, BV) { \
  int tap_ = (sv) >> 2, cs_ = (sv) & 3; \
  int ky_ = tap_ / 3, kx_ = tap_ - 3*ky_; \
  int ao_ = ((ky_*Sp + kx_) << 7) + (cs_ << 5); \
  _Pragma("unroll") for (int mf = 0; mf < 2; ++mf) \
    if (mf < mfc) AV[mf] = *(const bf16x8*)(lb + aoff[mf] + ao_); \
  _Pragma("unroll") for (int nt = 0; nt < 7; ++nt) \
    BV[nt] = *(const bf16x8*)(wb + (size_t)((nt)*36 + (sv))*512); }

#define CONV_MFMA(AV, BV) { \
  _Pragma("unroll") for (int nt = 0; nt < 7; ++nt) \
    _Pragma("unroll") for (int mf = 0; mf < 2; ++mf) \
      if (mf < mfc) acc[mf][nt] = __builtin_amdgcn_mfma_f32_16x16x32_bf16( \
                        AV[mf], BV[nt], acc[mf][nt], 0, 0, 0); }

    bf16x8 av0[2], bv0[7], av1[2], bv1[7];
    CONV_LOAD(0, av0, bv0);
    for (int s = 0; s < 36; s += 2) {
      CONV_LOAD(s+1, av1, bv1);
      CONV_MFMA(av0, bv0);
      if (s+2 < 36) CONV_LOAD(s+2, av0, bv0);
      CONV_MFMA(av1, bv1);
    }
#undef CONV_LOAD
#undef CONV_MFMA

    // stage acc -> LDS [n][69]
    #pragma unroll
    for (int mf = 0; mf < 2; ++mf) {
      if (mf < mfc) {
        #pragma unroll
        for (int nt = 0; nt < 7; ++nt) {
          const int n = nhalf*112 + nt*16 + mi;
          if (n < 196) {
            #pragma unroll
            for (int r = 0; r < 4; ++r) {
              const int p = mhalf*32 + mf*16 + q*4 + r;
              gl[n*69 + p] = acc[mf][nt][r];
            }
          }
        }
      }
    }
  }
  __syncthreads();

  // gate phase: wave w handles unit-group w, lanes = pixels 0..63
  const int p2 = lane;           // pixel within tile
  const int grp = wave;          // 0..3 -> units 13,13,13,10
  if (p2 < SS) {
    const int y = ty0 + (p2 >> lwsh), xx = tx0 + (p2 & msk);
    const int pix = y*S + xx;
    const float* bb2 = cfg.bias[lvl];
    const float* cp  = cfg.cpre[lvl];
    const int ch0 = grp*13, chend = (grp == 3) ? 49 : grp*13 + 13;
    for (int ch = ch0; ch < chend; ++ch) {
      float ci  = gl[ch*69 + p2]        + bb2[ch];
      float cf  = gl[(ch+49)*69 + p2]   + bb2[ch+49];
      float co_ = gl[(ch+98)*69 + p2]   + bb2[ch+98];
      float cg  = gl[(ch+147)*69 + p2]  + bb2[ch+147];
      float ig = 1.f/(1.f + __expf(-ci));
      float fg = 1.f/(1.f + __expf(-cf));
      float og = 1.f/(1.f + __expf(-co_));
      float g  = 1.f - 2.f/(__expf(2.f*cg) + 1.f);
      size_t e = ((size_t)b*49 + ch)*SS + pix;
      float cpv = cp[e];
      float cn = fg*cpv + ig*g;
      float hn = og * (1.f - 2.f/(__expf(2.f*cn) + 1.f));
      dout[cfg.h_off[lvl] + e] = hn;
      dout[cfg.c_off[lvl] + e] = cn;
    }
  }
}

// ---------------------------------------------------------------------------
extern "C" void kernel_launch(void* const* d_in, const int* in_sizes, int n_in,
                              void* d_out, int out_size, void* d_ws, size_t ws_size,
                              hipStream_t stream)
{
  const float *x[6], *xp[6], *h[6], *cpre[6], *w[6], *bias[6];
  for (int l = 0; l < 6; ++l) {
    x[l]    = (const float*)d_in[6*l + 0];
    xp[l]   = (const float*)d_in[6*l + 1];
    h[l]    = (const float*)d_in[6*l + 2];
    cpre[l] = (const float*)d_in[6*l + 3];
    w[l]    = (const float*)d_in[6*l + 4];
    bias[l] = (const float*)d_in[6*l + 5];
  }
  static const int SL[6] = {64,32,16,8,4,2};
  static const int CL[6] = {512,1024,512,256,256,256};
  int NSPL[6] = {8,16,16,1,1,1};

  long long hsz[6], lstm_off[6], h_off[6], poff[6];
  long long a1 = 0, a3 = 0;
  for (int l = 0; l < 6; ++l) {
    int S = SL[l], Sp = S + 2;
    hsz[l] = 8LL*49*S*S;
    lstm_off[l] = a1; a1 += 8LL*Sp*Sp*128;
    h_off[l]    = a3; a3 += hsz[l];
  }
  long long pa = 0;
  for (int l = 0; l < 6; ++l) { poff[l] = pa; pa += (long long)NSPL[l]*hsz[l]; }
  {
    long long need = a1*2 + 6LL*258048*2 + pa*2;
    if (need > (long long)ws_size) {      // fallback to smaller split config
      NSPL[0] = 4; NSPL[1] = 8; NSPL[2] = 16;
      pa = 0;
      for (int l = 0; l < 6; ++l) { poff[l] = pa; pa += (long long)NSPL[l]*hsz[l]; }
    }
  }
  const long long GRP = a3;            // floats per output group
  const long long LSTM_ELEMS = a1;     // bf16 elements

  uint16_t* lstm  = (uint16_t*)d_ws;
  uint16_t* wpack = (uint16_t*)((char*)d_ws + LSTM_ELEMS*2);
  _Float16* partial = (_Float16*)((char*)d_ws + LSTM_ELEMS*2 + 6LL*258048*2);
  float* dout = (float*)d_out;

  // corr (all levels, one launch)
  {
    CorrCfg ccfg;
    // big levels 0,1: 32x16 tiles -> l0: (64/16)*(64/32)=8 tiles, l1: 2 tiles
    static const int tpb2[2] = {8, 2};
    static const int txx2[2] = {2, 1};
    for (int l = 0; l < 6; ++l) { ccfg.gx[l] = x[l]; ccfg.gxp[l] = xp[l]; }
    int start = 0;
    for (int l = 0; l < 2; ++l) {
      ccfg.wg_start[l] = start;
      ccfg.S[l] = SL[l]; ccfg.C[l] = CL[l];
      ccfg.tiles_x[l] = txx2[l]; ccfg.tiles_pb[l] = tpb2[l];
      ccfg.cpl[l] = CL[l]/NSPL[l];
      ccfg.poff[l] = poff[l];
      start += NSPL[l]*8*tpb2[l];
    }
    ccfg.mid_start = start;
    ccfg.mcpl = CL[2]/NSPL[2];
    ccfg.mpoff = poff[2];
    start += NSPL[2]*8;
    for (int l = 0; l < 3; ++l) {
      ccfg.small_start[l] = start;
      ccfg.sS[l] = SL[l+3]; ccfg.sC[l] = CL[l+3];
      ccfg.sNspl[l] = NSPL[l+3];
      ccfg.spoff[l] = poff[l+3];
      start += (int)((NSPL[l+3]*hsz[l+3] + 255)/256);
    }
    corr_kernel<<<start, 256, 0, stream>>>(ccfg, partial);
  }
  // zero lstm_in (halo + channel pad), then weight pack
  (void)hipMemsetAsync(lstm, 0, (size_t)LSTM_ELEMS*2, stream);
  pack_w_kernel<<<6048, 256, 0, stream>>>(w[0],w[1],w[2],w[3],w[4],w[5], wpack);
  // pass2: partial sums -> leaky -> corr out + lstm_in (coalesced via LDS)
  {
    P2Cfg p2; int start = 0;
    static const int PXGL[6] = {32,64,64,64,16,4};
    static const int LGL[6]  = {5,6,6,6,4,2};
    for (int l = 0; l < 6; ++l) {
      p2.blk_start[l] = start;
      int gpb = (SL[l]*SL[l]) / PXGL[l]; if (gpb < 1) gpb = 1;
      p2.gpb[l] = gpb;
      start += 8 * gpb;
      p2.S[l] = SL[l]; p2.nsplit[l] = NSPL[l];
      p2.pxg[l] = PXGL[l]; p2.lg[l] = LGL[l];
      p2.poff[l] = poff[l]; p2.lstm_off[l] = lstm_off[l];
      p2.corr_off[l] = 2*GRP + h_off[l];
      p2.h[l] = h[l];
    }
    p2.blk_start[6] = start;
    pass2_kernel<<<start, 256, 0, stream>>>(p2, partial, (uint32_t*)lstm, dout);
  }
  // fused conv + gates (all levels, one launch)
  {
    CCfg cc;
    static const int ctpb[6] = {64, 16, 4, 1, 1, 1};
    static const int ctx[6]  = {4, 2, 1, 1, 1, 1};
    static const int clw[6]  = {4, 4, 4, 3, 2, 1};
    static const int cmfc[6] = {2, 2, 2, 2, 1, 1};
    static const int cmg[6]  = {2, 2, 2, 2, 1, 1};
    int start = 0;
    for (int l = 0; l < 6; ++l) {
      cc.wg_start[l] = start; start += 8*ctpb[l];
      cc.S[l] = SL[l]; cc.tiles_x[l] = ctx[l]; cc.tiles_pb[l] = ctpb[l];
      cc.lwsh[l] = clw[l]; cc.mfc[l] = cmfc[l]; cc.mgrp[l] = cmg[l];
      cc.lstm_off[l] = lstm_off[l];
      cc.wp_off[l] = 258048LL*l;
      cc.h_off[l] = h_off[l];
      cc.c_off[l] = GRP + h_off[l];
      cc.cpre[l] = cpre[l];
      cc.bias[l] = bias[l];
    }
    cc.wg_start[6] = start;
    conv_kernel<<<start, 256, 0, stream>>>(cc, lstm, wpack, dout);
  }
  (void)in_sizes; (void)n_in; (void)out_size; (void)ws_size;
}

// Round 10
// 430.836 us; speedup vs baseline: 1.2024x; 1.0087x over previous
//
#include <hip/hip_runtime.h>
#include <stdint.h>

#define DEV __device__ __forceinline__

typedef _Float16 half2_t __attribute__((ext_vector_type(2)));
typedef _Float16 half4_t __attribute__((ext_vector_type(4)));
typedef __bf16   bf16x8  __attribute__((ext_vector_type(8)));
typedef float    floatx4 __attribute__((ext_vector_type(4)));
typedef float    floatx2 __attribute__((ext_vector_type(2)));

DEV float fdot2f(half2_t a, half2_t b, float c) {
#if __has_builtin(__builtin_amdgcn_fdot2)
  return __builtin_amdgcn_fdot2(a, b, c, false);
#else
  return c + (float)a[0] * (float)b[0] + (float)a[1] * (float)b[1];
#endif
}

DEV half2_t pkh2(float a, float b) {
#if __has_builtin(__builtin_amdgcn_cvt_pkrtz)
  return __builtin_bit_cast(half2_t, __builtin_amdgcn_cvt_pkrtz(a, b));
#else
  half2_t r; r[0] = (_Float16)a; r[1] = (_Float16)b; return r;
#endif
}

DEV uint32_t f2bf(float f) {  // fp32 -> bf16 bits, RNE
  uint32_t u = __float_as_uint(f);
  return (u + 0x7FFFu + ((u >> 16) & 1u)) >> 16;
}

// Raw workgroup barrier: drains LDS ops only (lgkmcnt), NOT vmcnt.
DEV void tile_barrier() {
  __builtin_amdgcn_sched_barrier(0);
  asm volatile("s_waitcnt lgkmcnt(0)" ::: "memory");
  __builtin_amdgcn_s_barrier();
  __builtin_amdgcn_sched_barrier(0);
}

// ---------------------------------------------------------------------------
// Correlation (all levels) + AUX (lstm memset, weight pack) in ONE launch.
// Aux blocks are appended AFTER corr blocks: they fill freed slots as corr
// blocks retire, hiding pack+memset (and 2 launch gaps) under corr's
// latency-bound tail. Stream order still gives memset->pass2, pack->conv.
// Corr paths byte-identical to round 8/9 (proven: 112 µs, VGPR=128).
// ---------------------------------------------------------------------------
struct CorrCfg {
  const float* gx[6]; const float* gxp[6];
  int wg_start[2];     // big levels 0,1
  int mid_start;       // level 2
  int small_start[3];  // levels 3-5
  int S[2], C[2], tiles_x[2], tiles_pb[2], cpl[2];
  int mcpl;
  int sS[3], sC[3], sNspl[3];
  long long poff[2], mpoff, spoff[3];
  // aux
  const float* w[6];
  uint16_t* wpk;
  uint16_t* lstmz;
  int aux_start, nmemset_blk;
};

__global__ __launch_bounds__(256)
void corr_kernel(CorrCfg cfg, _Float16* __restrict__ partial)
{
  __shared__ half2_t ldsbuf[2][2][22*40] __attribute__((aligned(16)));
  const int tid = threadIdx.x;
  int wg = blockIdx.x;

  if (wg >= cfg.aux_start) {
    // ---- aux path: lstm zero-fill, then weight pack ----
    int aw = wg - cfg.aux_start;
    if (aw < cfg.nmemset_blk) {
      floatx4* p = (floatx4*)cfg.lstmz;
      p[(size_t)aw*256 + tid] = (floatx4)0.f;
    } else {
      int idx = (aw - cfg.nmemset_blk)*256 + tid;
      int lvl = idx / 258048;
      int e = idx - lvl*258048;
      const float* W = cfg.w[lvl];
      int j = e & 7, lane = (e >> 3) & 63, rest = e >> 9;
      int s = rest % 36, tt = rest / 36;
      int n  = tt*16 + (lane & 15);
      int ch = (s & 3)*32 + (lane >> 4)*8 + j;
      int tap = s >> 2, ky = tap/3, kx = tap - 3*ky;
      float v = 0.f;
      if (n < 196 && ch < 98) v = W[((n*98 + ch)*3 + ky)*3 + kx];
      cfg.wpk[idx] = (uint16_t)f2bf(v);
    }
    return;
  }

  if (wg >= cfg.small_start[0]) {
    // ---- small path (levels 3-5) ----
    int lvl = (wg >= cfg.small_start[2]) ? 2 : (wg >= cfg.small_start[1]) ? 1 : 0;
    long long i = (long long)(wg - cfg.small_start[lvl])*256 + tid;
    const int S = cfg.sS[lvl], C = cfg.sC[lvl], SS = S*S;
    const int nsp = cfg.sNspl[lvl];
    const long long per = (long long)8*49*SS;
    if (i >= (long long)nsp*per) return;
    int sp = (int)(i / per);
    long long rem = i - (long long)sp*per;
    const int cpl = C / nsp, cbase = sp * cpl;
    const float* X  = cfg.gx[lvl+3];
    const float* XP = cfg.gxp[lvl+3];
    int xc_ = (int)(rem % S); int yc = (int)((rem/S) % S);
    int d = (int)((rem/SS) % 49); int b = (int)(rem/((long long)49*SS));
    int yy = yc + d/7 - 3, xx = xc_ + (d%7) - 3;
    float s = 0.f;
    if (yy >= 0 && yy < S && xx >= 0 && xx < S) {
      const float* xb = X  + ((size_t)b*C + cbase)*SS + (size_t)yc*S + xc_;
      const float* pb = XP + ((size_t)b*C + cbase)*SS + (size_t)yy*S + xx;
      #pragma unroll 8
      for (int c = 0; c < cpl; ++c) s += xb[(size_t)c*SS] * pb[(size_t)c*SS];
    }
    partial[cfg.spoff[lvl] + (long long)sp*per + rem] = (_Float16)s;
    return;
  }

  if (wg >= cfg.mid_start) {
    // ---- mid path (level 2, S=16, C=512): 1 px/thread, b32 windows ----
    constexpr int NT = 256, MS = 16, MC = 512;
    constexpr int ROWS = 22, COLS = 22, ST = 23;
    constexpr int SLOTS = ROWS * 6 * 2;       // 264
    constexpr int PER = 2;
    int rel = wg - cfg.mid_start;
    const int cpl = cfg.mcpl;
    const int sp = rel >> 3;
    const int b = rel & 7;
    const int tx = tid & 15, ty = tid >> 4;
    const int cbase = sp * cpl;
    const size_t SS = (size_t)MS*MS;
    const float* Xb  = cfg.gx[2]  + (size_t)b*MC*SS;
    const float* XPb = cfg.gxp[2] + (size_t)b*MC*SS;
    const size_t qoff = (size_t)ty*MS + tx;

    int f_go[PER], f_base[PER], f_col0[PER], f_pr[PER];
    bool f_ok[PER], f_val[PER];
    #pragma unroll
    for (int s = 0; s < PER; ++s) {
      int i = tid + s*NT;
      bool val = (i < SLOTS);
      int ii = val ? i : 0;
      int pr = ii & 1;
      int rest = ii >> 1;
      int q = rest % 6;
      int r = rest / 6;
      int gy = r - 3;
      int gx0 = -4 + 4*q;
      bool ok = val && gy >= 0 && gy < MS && gx0 >= 0 && (gx0 + 3) < MS;
      f_val[s] = val; f_ok[s] = ok; f_pr[s] = pr;
      f_go[s] = ok ? gy*MS + gx0 : 0;
      f_col0[s] = 4*q - 1;
      f_base[s] = r*ST;
    }

    float acc[49];
    #pragma unroll
    for (int d = 0; d < 49; ++d) acc[d] = 0.f;
    half2_t pk[PER][4];
    half2_t xq0[2], xq1[2];

#define MFILL_LOADPK(c0v) { \
  _Pragma("unroll") for (int s = 0; s < PER; ++s) { \
    const float* p_ = XPb + (size_t)(cbase + (c0v) + 2*f_pr[s])*SS + f_go[s]; \
    floatx4 a_ = (floatx4)0.f, b2_ = (floatx4)0.f; \
    if (f_ok[s]) { a_ = *(const floatx4*)p_; b2_ = *(const floatx4*)(p_ + SS); } \
    _Pragma("unroll") for (int j = 0; j < 4; ++j) \
      pk[s][j] = pkh2(a_[j], b2_[j]); } }

#define MXLOADPK(dst, c0v) { \
  float t0_ = Xb[(size_t)(cbase + (c0v) + 0)*SS + qoff]; \
  float t1_ = Xb[(size_t)(cbase + (c0v) + 1)*SS + qoff]; \
  float t2_ = Xb[(size_t)(cbase + (c0v) + 2)*SS + qoff]; \
  float t3_ = Xb[(size_t)(cbase + (c0v) + 3)*SS + qoff]; \
  dst[0] = pkh2(t0_, t1_); dst[1] = pkh2(t2_, t3_); }

#define MFILL_STORE(bbv) { \
  _Pragma("unroll") for (int s = 0; s < PER; ++s) if (f_val[s]) { \
    half2_t* plane_ = &ldsbuf[bbv][f_pr[s]][0]; \
    _Pragma("unroll") for (int j = 0; j < 4; ++j) { \
      int col_ = f_col0[s] + j; \
      if (col_ >= 0 && col_ < COLS) \
        plane_[f_base[s] + col_] = pk[s][j]; } } }

#define MCOMPUTE(bbv, xq) { \
  _Pragma("unroll") for (int pr = 0; pr < 2; ++pr) { \
    half2_t xv = xq[pr]; \
    _Pragma("unroll") for (int di = 0; di < 7; ++di) { \
      const half2_t* row_ = &ldsbuf[bbv][pr][(ty+di)*ST + tx]; \
      _Pragma("unroll") for (int dj = 0; dj < 7; ++dj) \
        acc[di*7+dj] = fdot2f(xv, row_[dj], acc[di*7+dj]); } } }

    const int nchunk = cpl >> 2;
    MFILL_LOADPK(0); MXLOADPK(xq0, 0);
    MFILL_STORE(0);
    MFILL_LOADPK(4); MXLOADPK(xq1, 4);
    tile_barrier();
    for (int k = 0; k < nchunk; k += 2) {
      {
        if (k+1 < nchunk) MFILL_STORE(1);
        if (k+2 < nchunk) MFILL_LOADPK((k+2)*4);
        MCOMPUTE(0, xq0);
        if (k+2 < nchunk) MXLOADPK(xq0, (k+2)*4);
        tile_barrier();
      }
      if (k+1 < nchunk) {
        if (k+2 < nchunk) MFILL_STORE(0);
        if (k+3 < nchunk) MFILL_LOADPK((k+3)*4);
        MCOMPUTE(1, xq1);
        if (k+3 < nchunk) MXLOADPK(xq1, (k+3)*4);
        tile_barrier();
      }
    }
#undef MFILL_LOADPK
#undef MXLOADPK
#undef MFILL_STORE
#undef MCOMPUTE

    _Float16* P = partial + cfg.mpoff + ((size_t)sp*8 + b)*49*SS + qoff;
    #pragma unroll
    for (int d = 0; d < 49; ++d) P[(size_t)d*SS] = (_Float16)acc[d];
    return;
  }

  // ---- big path (levels 0,1): 32x16 tile, 2 px/thread, b64 windows ----
  {
    constexpr int NT = 256, TH = 16, TW = 32;
    constexpr int ROWS = TH + 6;            // 22
    constexpr int COLS = TW + 6;            // 38
    constexpr int QUADS = 10;
    constexpr int ST = TW + 8;              // 40 (even; bank-pair 20r+tx uniform)
    constexpr int SLOTS = ROWS * QUADS * 2; // 440
    constexpr int PER = 2;

    int lvl = (wg >= cfg.wg_start[1]) ? 1 : 0;
    wg -= cfg.wg_start[lvl];
    const float* X  = cfg.gx[lvl];
    const float* XP = cfg.gxp[lvl];
    const int S = cfg.S[lvl], C = cfg.C[lvl];
    const int txc = cfg.tiles_x[lvl], tpb = cfg.tiles_pb[lvl], cpl = cfg.cpl[lvl];
    const int per_split = 8 * tpb;
    const int sp = wg / per_split;
    const int rem = wg - sp*per_split;
    const int b = rem / tpb;
    const int t = rem - b*tpb;
    const int y0 = (t / txc) * TH, x0t = (t % txc) * TW;
    const int tx = tid & 15, ty = tid >> 4;
    const int cbase = sp * cpl;
    const size_t SS = (size_t)S*S;
    const float* Xb  = X  + (size_t)b*C*SS;
    const float* XPb = XP + (size_t)b*C*SS;
    const int py = y0 + ty, px = x0t + 2*tx;
    const size_t qoff = (size_t)py*S + px;

    int f_go[PER], f_base[PER], f_col0[PER], f_pr[PER];
    bool f_ok[PER], f_val[PER];
    #pragma unroll
    for (int s = 0; s < PER; ++s) {
      int i = tid + s*NT;
      bool val = (i < SLOTS);
      int ii = val ? i : 0;
      int pr = ii & 1;
      int rest = ii >> 1;
      int q = rest % QUADS;
      int r = rest / QUADS;
      int gy = y0 + r - 3;
      int gx0 = x0t - 4 + 4*q;
      bool ok = val && gy >= 0 && gy < S && gx0 >= 0 && (gx0 + 3) < S;
      f_val[s] = val; f_ok[s] = ok; f_pr[s] = pr;
      f_go[s] = ok ? gy*S + gx0 : 0;
      f_col0[s] = 4*q - 1;
      f_base[s] = r*ST;
    }

    floatx2 acc[49];
    #pragma unroll
    for (int d = 0; d < 49; ++d) acc[d] = (floatx2)0.f;
    half2_t pk[PER][4];
    half2_t xq0[4], xq1[4];

#define FILL_LOADPK(c0v) { \
  _Pragma("unroll") for (int s = 0; s < PER; ++s) { \
    const float* p_ = XPb + (size_t)(cbase + (c0v) + 2*f_pr[s])*SS + f_go[s]; \
    floatx4 a_ = (floatx4)0.f, b2_ = (floatx4)0.f; \
    if (f_ok[s]) { a_ = *(const floatx4*)p_; b2_ = *(const floatx4*)(p_ + SS); } \
    _Pragma("unroll") for (int j = 0; j < 4; ++j) \
      pk[s][j] = pkh2(a_[j], b2_[j]); } }

#define XLOADPK(dst, c0v) { \
  floatx2 t0_ = *(const floatx2*)(Xb + (size_t)(cbase + (c0v) + 0)*SS + qoff); \
  floatx2 t1_ = *(const floatx2*)(Xb + (size_t)(cbase + (c0v) + 1)*SS + qoff); \
  floatx2 t2_ = *(const floatx2*)(Xb + (size_t)(cbase + (c0v) + 2)*SS + qoff); \
  floatx2 t3_ = *(const floatx2*)(Xb + (size_t)(cbase + (c0v) + 3)*SS + qoff); \
  dst[0] = pkh2(t0_.x, t1_.x); dst[1] = pkh2(t0_.y, t1_.y); \
  dst[2] = pkh2(t2_.x, t3_.x); dst[3] = pkh2(t2_.y, t3_.y); }

#define FILL_STORE(bbv) { \
  _Pragma("unroll") for (int s = 0; s < PER; ++s) if (f_val[s]) { \
    half2_t* plane_ = &ldsbuf[bbv][f_pr[s]][0]; \
    _Pragma("unroll") for (int j = 0; j < 4; ++j) { \
      int col_ = f_col0[s] + j; \
      if (col_ >= 0 && col_ < COLS) \
        plane_[f_base[s] + col_] = pk[s][j]; } } }

#define COMPUTE(bbv, xq) { \
  _Pragma("unroll") for (int pr = 0; pr < 2; ++pr) { \
    half2_t xqa = xq[2*pr], xqb = xq[2*pr+1]; \
    _Pragma("unroll") for (int di = 0; di < 7; ++di) { \
      const half2_t* row_ = &ldsbuf[bbv][pr][(ty+di)*ST + 2*tx]; \
      half2_t L_[8]; \
      _Pragma("unroll") for (int k = 0; k < 4; ++k) { \
        half4_t v_ = *(const half4_t*)(row_ + 2*k); \
        L_[2*k]   = __builtin_shufflevector(v_, v_, 0, 1); \
        L_[2*k+1] = __builtin_shufflevector(v_, v_, 2, 3); } \
      _Pragma("unroll") for (int dj = 0; dj < 7; ++dj) { \
        acc[di*7+dj].x = fdot2f(xqa, L_[dj],   acc[di*7+dj].x); \
        acc[di*7+dj].y = fdot2f(xqb, L_[dj+1], acc[di*7+dj].y); } } } }

    const int nchunk = cpl >> 2;
    FILL_LOADPK(0); XLOADPK(xq0, 0);
    FILL_STORE(0);
    FILL_LOADPK(4); XLOADPK(xq1, 4);
    tile_barrier();
    for (int k = 0; k < nchunk; k += 2) {
      {
        if (k+1 < nchunk) FILL_STORE(1);
        if (k+2 < nchunk) FILL_LOADPK((k+2)*4);
        COMPUTE(0, xq0);
        if (k+2 < nchunk) XLOADPK(xq0, (k+2)*4);
        tile_barrier();
      }
      if (k+1 < nchunk) {
        if (k+2 < nchunk) FILL_STORE(0);
        if (k+3 < nchunk) FILL_LOADPK((k+3)*4);
        COMPUTE(1, xq1);
        if (k+3 < nchunk) XLOADPK(xq1, (k+3)*4);
        tile_barrier();
      }
    }
#undef FILL_LOADPK
#undef XLOADPK
#undef FILL_STORE
#undef COMPUTE

    _Float16* P = partial + cfg.poff[lvl] + ((size_t)sp*8 + b)*49*SS + qoff;
    #pragma unroll
    for (int d = 0; d < 49; ++d) {
      half2_t pko = pkh2(acc[d].x, acc[d].y);
      *(uint32_t*)(P + (size_t)d*SS) = *(const uint32_t*)&pko;
    }
  }
}

// ---------------------------------------------------------------------------
// Pass2: stage A vectorized 4 px/thread (half4 split reads, float4 h/corr IO),
// stage B packed bf16x2 u32 stores into channels-last lstm_in. [r9, proven]
// ---------------------------------------------------------------------------
struct P2Cfg {
  int blk_start[7];
  int S[6], nsplit[6], pxg[6], lg[6], gpb[6];
  long long poff[6], lstm_off[6], corr_off[6];
  const float* h[6];
};
__global__ __launch_bounds__(256)
void pass2_kernel(P2Cfg cfg, const _Float16* __restrict__ partial,
                  uint32_t* __restrict__ lstm, float* __restrict__ dout)
{
  __shared__ float lds[64*99];
  int blk = blockIdx.x;
  int lvl = 0;
  while (lvl < 5 && blk >= cfg.blk_start[lvl+1]) ++lvl;
  int rel = blk - cfg.blk_start[lvl];
  const int S = cfg.S[lvl], Sp = S + 2, SS = S*S;
  const int PXG = cfg.pxg[lvl], lg = cfg.lg[lvl], gpb = cfg.gpb[lvl];
  const int b = rel / gpb, g = rel - b*gpb;
  const int pixbase = g * PXG;
  const int tid = threadIdx.x;
  const int nsp = cfg.nsplit[lvl];
  const size_t spstride = (size_t)8*49*SS;
  // stage A: 4 px per thread
  const int quads = PXG >> 2;
  const int lq = lg - 2;
  for (int e = tid; e < quads*98; e += 256) {
    int qx = e & (quads - 1);
    int ch = e >> lq;
    int pix = pixbase + 4*qx;
    floatx4 v;
    if (ch < 49) {
      const _Float16* P = partial + cfg.poff[lvl] + ((size_t)b*49 + ch)*SS + pix;
      floatx4 s = (floatx4)0.f;
      for (int sp = 0; sp < nsp; ++sp) {
        half4_t pv = *(const half4_t*)(P + (size_t)sp*spstride);
        s[0] += (float)pv[0]; s[1] += (float)pv[1];
        s[2] += (float)pv[2]; s[3] += (float)pv[3];
      }
      #pragma unroll
      for (int j = 0; j < 4; ++j) s[j] = s[j] < 0.f ? 0.01f*s[j] : s[j];
      *(floatx4*)(dout + cfg.corr_off[lvl] + ((size_t)b*49 + ch)*SS + pix) = s;
      v = s;
    } else {
      v = *(const floatx4*)(cfg.h[lvl] + ((size_t)b*49 + (ch - 49))*SS + pix);
    }
    int pxl = 4*qx;
    lds[(pxl+0)*99 + ch] = v[0];
    lds[(pxl+1)*99 + ch] = v[1];
    lds[(pxl+2)*99 + ch] = v[2];
    lds[(pxl+3)*99 + ch] = v[3];
  }
  __syncthreads();
  // stage B
  uint32_t* Lb = lstm + (cfg.lstm_off[lvl] >> 1);
  for (int f = tid; f < (PXG << 6); f += 256) {
    int pxl = f >> 6, c2 = f & 63;
    int pix = pixbase + pxl;
    int y = pix / S, x = pix - y*S;
    int c0 = 2*c2, c1 = c0 + 1;
    float v0 = c0 < 98 ? lds[pxl*99 + c0] : 0.f;
    float v1 = c1 < 98 ? lds[pxl*99 + c1] : 0.f;
    Lb[((size_t)(b*Sp + y + 1)*Sp + (x + 1))*64 + c2] = f2bf(v0) | (f2bf(v1) << 16);
  }
}

// ---------------------------------------------------------------------------
// FUSED Conv 3x3 (98->196) + LSTM gates. [r8 structure] + dead-N-tile skip:
// nhalf=1,nt=6 covers n in [208,224) — all >=196, zero weights -> skip its
// loads and MFMAs entirely (ntc = 7-nhalf), saving ~7% of conv work.
// ---------------------------------------------------------------------------
struct CCfg {
  int wg_start[7];
  int S[6], tiles_x[6], tiles_pb[6], lwsh[6], mfc[6], mgrp[6];
  long long lstm_off[6], wp_off[6], h_off[6], c_off[6];
  const float* cpre[6]; const float* bias[6];
};
__global__ __launch_bounds__(256)
void conv_kernel(CCfg cfg, const uint16_t* __restrict__ lstm,
                 const uint16_t* __restrict__ wpack, float* __restrict__ dout)
{
  __shared__ float gl[224*69];   // [n][p] staging, 61.8 KB
  int wg = blockIdx.x;
  int lvl = 0;
  while (lvl < 5 && wg >= cfg.wg_start[lvl+1]) ++lvl;
  wg -= cfg.wg_start[lvl];
  const int S = cfg.S[lvl], Sp = S + 2;
  const int lwsh = cfg.lwsh[lvl], msk = (1 << lwsh) - 1;
  const int tpb = cfg.tiles_pb[lvl];
  const int b = wg / tpb, t = wg - b*tpb;
  const int ty0 = (t / cfg.tiles_x[lvl]) << (6 - lwsh);
  const int tx0 = (t % cfg.tiles_x[lvl]) << lwsh;
  const int tid = threadIdx.x;
  const int wave = tid >> 6, lane = tid & 63;
  const int nhalf = wave & 1, mhalf = wave >> 1;
  const int mfc = cfg.mfc[lvl];
  const bool active = (mhalf < cfg.mgrp[lvl]);
  const int mi = lane & 15, q = lane >> 4;
  const int SS = S*S;
  const int ntc = 7 - nhalf;     // skip dead N-tile (n>=208) on nhalf=1

  if (active) {
    const uint16_t* lb = lstm + cfg.lstm_off[lvl] + (size_t)b*Sp*Sp*128;
    int aoff[2];
    #pragma unroll
    for (int mf = 0; mf < 2; ++mf) {
      int p = mhalf*32 + mf*16 + mi;
      int pc = p < SS ? p : 0;                 // clamp (small-level pad)
      int y = ty0 + (pc >> lwsh), xx = tx0 + (pc & msk);
      aoff[mf] = (y*Sp + xx)*128 + q*8;
    }
    const uint16_t* wb = wpack + cfg.wp_off[lvl]
                       + (size_t)(nhalf*7)*36*512 + (size_t)lane*8;
    floatx4 acc[2][7];
    #pragma unroll
    for (int mf = 0; mf < 2; ++mf)
      #pragma unroll
      for (int nt = 0; nt < 7; ++nt) acc[mf][nt] = (floatx4)0.0f;

#define CONV_LOAD(sv, AV, BV) { \
  int tap_ = (sv) >> 2, cs_ = (sv) & 3; \
  int ky_ = tap_ / 3, kx_ = tap_ - 3*ky_; \
  int ao_ = ((ky_*Sp + kx_) << 7) + (cs_ << 5); \
  _Pragma("unroll") for (int mf = 0; mf < 2; ++mf) \
    if (mf < mfc) AV[mf] = *(const bf16x8*)(lb + aoff[mf] + ao_); \
  _Pragma("unroll") for (int nt = 0; nt < 7; ++nt) \
    if (nt < ntc) BV[nt] = *(const bf16x8*)(wb + (size_t)((nt)*36 + (sv))*512); }

#define CONV_MFMA(AV, BV) { \
  _Pragma("unroll") for (int nt = 0; nt < 7; ++nt) \
    _Pragma("unroll") for (int mf = 0; mf < 2; ++mf) \
      if (nt < ntc && mf < mfc) acc[mf][nt] = __builtin_amdgcn_mfma_f32_16x16x32_bf16( \
                        AV[mf], BV[nt], acc[mf][nt], 0, 0, 0); }

    bf16x8 av0[2], bv0[7], av1[2], bv1[7];
    CONV_LOAD(0, av0, bv0);
    for (int s = 0; s < 36; s += 2) {
      CONV_LOAD(s+1, av1, bv1);
      CONV_MFMA(av0, bv0);
      if (s+2 < 36) CONV_LOAD(s+2, av0, bv0);
      CONV_MFMA(av1, bv1);
    }
#undef CONV_LOAD
#undef CONV_MFMA

    // stage acc -> LDS [n][69]
    #pragma unroll
    for (int mf = 0; mf < 2; ++mf) {
      if (mf < mfc) {
        #pragma unroll
        for (int nt = 0; nt < 7; ++nt) {
          const int n = nhalf*112 + nt*16 + mi;
          if (n < 196) {
            #pragma unroll
            for (int r = 0; r < 4; ++r) {
              const int p = mhalf*32 + mf*16 + q*4 + r;
              gl[n*69 + p] = acc[mf][nt][r];
            }
          }
        }
      }
    }
  }
  __syncthreads();

  // gate phase: wave w handles unit-group w, lanes = pixels 0..63
  const int p2 = lane;           // pixel within tile
  const int grp = wave;          // 0..3 -> units 13,13,13,10
  if (p2 < SS) {
    const int y = ty0 + (p2 >> lwsh), xx = tx0 + (p2 & msk);
    const int pix = y*S + xx;
    const float* bb2 = cfg.bias[lvl];
    const float* cp  = cfg.cpre[lvl];
    const int ch0 = grp*13, chend = (grp == 3) ? 49 : grp*13 + 13;
    for (int ch = ch0; ch < chend; ++ch) {
      float ci  = gl[ch*69 + p2]        + bb2[ch];
      float cf  = gl[(ch+49)*69 + p2]   + bb2[ch+49];
      float co_ = gl[(ch+98)*69 + p2]   + bb2[ch+98];
      float cg  = gl[(ch+147)*69 + p2]  + bb2[ch+147];
      float ig = 1.f/(1.f + __expf(-ci));
      float fg = 1.f/(1.f + __expf(-cf));
      float og = 1.f/(1.f + __expf(-co_));
      float g  = 1.f - 2.f/(__expf(2.f*cg) + 1.f);
      size_t e = ((size_t)b*49 + ch)*SS + pix;
      float cpv = cp[e];
      float cn = fg*cpv + ig*g;
      float hn = og * (1.f - 2.f/(__expf(2.f*cn) + 1.f));
      dout[cfg.h_off[lvl] + e] = hn;
      dout[cfg.c_off[lvl] + e] = cn;
    }
  }
}

// ---------------------------------------------------------------------------
extern "C" void kernel_launch(void* const* d_in, const int* in_sizes, int n_in,
                              void* d_out, int out_size, void* d_ws, size_t ws_size,
                              hipStream_t stream)
{
  const float *x[6], *xp[6], *h[6], *cpre[6], *w[6], *bias[6];
  for (int l = 0; l < 6; ++l) {
    x[l]    = (const float*)d_in[6*l + 0];
    xp[l]   = (const float*)d_in[6*l + 1];
    h[l]    = (const float*)d_in[6*l + 2];
    cpre[l] = (const float*)d_in[6*l + 3];
    w[l]    = (const float*)d_in[6*l + 4];
    bias[l] = (const float*)d_in[6*l + 5];
  }
  static const int SL[6] = {64,32,16,8,4,2};
  static const int CL[6] = {512,1024,512,256,256,256};
  int NSPL[6] = {8,16,16,1,1,1};

  long long hsz[6], lstm_off[6], h_off[6], poff[6];
  long long a1 = 0, a3 = 0;
  for (int l = 0; l < 6; ++l) {
    int S = SL[l], Sp = S + 2;
    hsz[l] = 8LL*49*S*S;
    lstm_off[l] = a1; a1 += 8LL*Sp*Sp*128;
    h_off[l]    = a3; a3 += hsz[l];
  }
  long long pa = 0;
  for (int l = 0; l < 6; ++l) { poff[l] = pa; pa += (long long)NSPL[l]*hsz[l]; }
  {
    long long need = a1*2 + 6LL*258048*2 + pa*2;
    if (need > (long long)ws_size) {      // fallback to smaller split config
      NSPL[0] = 4; NSPL[1] = 8; NSPL[2] = 16;
      pa = 0;
      for (int l = 0; l < 6; ++l) { poff[l] = pa; pa += (long long)NSPL[l]*hsz[l]; }
    }
  }
  const long long GRP = a3;            // floats per output group
  const long long LSTM_ELEMS = a1;     // bf16 elements

  uint16_t* lstm  = (uint16_t*)d_ws;
  uint16_t* wpack = (uint16_t*)((char*)d_ws + LSTM_ELEMS*2);
  _Float16* partial = (_Float16*)((char*)d_ws + LSTM_ELEMS*2 + 6LL*258048*2);
  float* dout = (float*)d_out;

  // corr + memset(lstm) + pack_w (one launch; aux blocks trail corr blocks)
  {
    CorrCfg ccfg;
    static const int tpb2[2] = {8, 2};
    static const int txx2[2] = {2, 1};
    for (int l = 0; l < 6; ++l) { ccfg.gx[l] = x[l]; ccfg.gxp[l] = xp[l]; }
    int start = 0;
    for (int l = 0; l < 2; ++l) {
      ccfg.wg_start[l] = start;
      ccfg.S[l] = SL[l]; ccfg.C[l] = CL[l];
      ccfg.tiles_x[l] = txx2[l]; ccfg.tiles_pb[l] = tpb2[l];
      ccfg.cpl[l] = CL[l]/NSPL[l];
      ccfg.poff[l] = poff[l];
      start += NSPL[l]*8*tpb2[l];
    }
    ccfg.mid_start = start;
    ccfg.mcpl = CL[2]/NSPL[2];
    ccfg.mpoff = poff[2];
    start += NSPL[2]*8;
    for (int l = 0; l < 3; ++l) {
      ccfg.small_start[l] = start;
      ccfg.sS[l] = SL[l+3]; ccfg.sC[l] = CL[l+3];
      ccfg.sNspl[l] = NSPL[l+3];
      ccfg.spoff[l] = poff[l+3];
      start += (int)((NSPL[l+3]*hsz[l+3] + 255)/256);
    }
    // aux: lstm zero (16B stores) + weight pack
    for (int l = 0; l < 6; ++l) ccfg.w[l] = w[l];
    ccfg.wpk = wpack;
    ccfg.lstmz = lstm;
    ccfg.aux_start = start;
    ccfg.nmemset_blk = (int)(LSTM_ELEMS / 8 / 256);   // LSTM_ELEMS*2 B / 16 / 256
    int npack_blk = 6048;
    int grid = start + ccfg.nmemset_blk + npack_blk;
    corr_kernel<<<grid, 256, 0, stream>>>(ccfg, partial);
  }
  // pass2: partial sums -> leaky -> corr out + lstm_in (coalesced via LDS)
  {
    P2Cfg p2; int start = 0;
    static const int PXGL[6] = {32,64,64,64,16,4};
    static const int LGL[6]  = {5,6,6,6,4,2};
    for (int l = 0; l < 6; ++l) {
      p2.blk_start[l] = start;
      int gpb = (SL[l]*SL[l]) / PXGL[l]; if (gpb < 1) gpb = 1;
      p2.gpb[l] = gpb;
      start += 8 * gpb;
      p2.S[l] = SL[l]; p2.nsplit[l] = NSPL[l];
      p2.pxg[l] = PXGL[l]; p2.lg[l] = LGL[l];
      p2.poff[l] = poff[l]; p2.lstm_off[l] = lstm_off[l];
      p2.corr_off[l] = 2*GRP + h_off[l];
      p2.h[l] = h[l];
    }
    p2.blk_start[6] = start;
    pass2_kernel<<<start, 256, 0, stream>>>(p2, partial, (uint32_t*)lstm, dout);
  }
  // fused conv + gates (all levels, one launch)
  {
    CCfg cc;
    static const int ctpb[6] = {64, 16, 4, 1, 1, 1};
    static const int ctx[6]  = {4, 2, 1, 1, 1, 1};
    static const int clw[6]  = {4, 4, 4, 3, 2, 1};
    static const int cmfc[6] = {2, 2, 2, 2, 1, 1};
    static const int cmg[6]  = {2, 2, 2, 2, 1, 1};
    int start = 0;
    for (int l = 0; l < 6; ++l) {
      cc.wg_start[l] = start; start += 8*ctpb[l];
      cc.S[l] = SL[l]; cc.tiles_x[l] = ctx[l]; cc.tiles_pb[l] = ctpb[l];
      cc.lwsh[l] = clw[l]; cc.mfc[l] = cmfc[l]; cc.mgrp[l] = cmg[l];
      cc.lstm_off[l] = lstm_off[l];
      cc.wp_off[l] = 258048LL*l;
      cc.h_off[l] = h_off[l];
      cc.c_off[l] = GRP + h_off[l];
      cc.cpre[l] = cpre[l];
      cc.bias[l] = bias[l];
    }
    cc.wg_start[6] = start;
    conv_kernel<<<start, 256, 0, stream>>>(cc, lstm, wpack, dout);
  }
  (void)in_sizes; (void)n_in; (void)out_size; (void)ws_size;
}